// Round 1
// baseline (6909.777 us; speedup 1.0000x reference)
//
#include <hip/hip_runtime.h>
#include <cstdint>
#include <cstddef>

#define NN      20000
#define RR      4
#define EE      40000
#define CIN     256
#define CEDGE   128
#define HIDW    512
#define OUTW    256
#define NH      8
#define DH      64
#define MEDGE   (RR*EE)
#define SCALEF  0.125f

// ---- ws layout (float elements) ----
// kqv region (30.72M) is reused later: h1 at 0..10.24M, edge-interm at 10.24M..30.72M
#define OFF_KQV   0ull
#define OFF_H1    0ull
#define OFF_EINT  10240000ull
#define OFF_H0    30720000ull
#define OFF_AGG   40960000ull
#define OFF_TMP   51200000ull
#define OFF_ALPHA 61440000ull
#define OFF_AMAX  62720000ull
#define OFF_DEN   62880000ull
#define WS_FLOATS 63040000ull

__device__ __forceinline__ unsigned enc_f(float f) {
    unsigned b = __float_as_uint(f);
    return b ^ (unsigned)(((int)b >> 31) | 0x80000000);
}
__device__ __forceinline__ float dec_f(unsigned u) {
    unsigned b = (u & 0x80000000u) ? (u ^ 0x80000000u) : ~u;
    return __uint_as_float(b);
}
__device__ __forceinline__ float gelu_exact(float x) {
    return 0.5f * x * (1.0f + erff(x * 0.70710678118654752f));
}

// ---------------- generic f32 GEMM: C = act(A@B + bias) [optional skip mix] ----------------
// A: M x K row-major (contiguous), B: K x N row-major, C: M x N.
// N % 64 == 0, K % 16 == 0 assumed. M guarded.
template<int ACT, bool SKIP>
__global__ __launch_bounds__(256) void gemm_f32(
    const float* __restrict__ A, const float* __restrict__ B,
    const float* __restrict__ bias, float* __restrict__ C,
    int M, int N, int K,
    const float* __restrict__ skipx, const float* __restrict__ gatep)
{
    __shared__ __align__(16) float As[16][68];  // [k][m]
    __shared__ __align__(16) float Bs[16][68];  // [k][n]
    const int t  = threadIdx.x;
    const int m0 = blockIdx.y * 64, n0 = blockIdx.x * 64;
    const int tm = (t & 15) * 4, tn = (t >> 4) * 4;
    const int la_r = t >> 2, la_c = (t & 3) * 4;   // A tile: 64 rows x 16 k
    const int lb_r = t >> 4, lb_c = (t & 15) * 4;  // B tile: 16 k x 64 cols
    const bool a_in = (m0 + la_r) < M;
    const float* Ap = A + (size_t)(m0 + la_r) * K + la_c;
    const float* Bp = B + (size_t)lb_r * N + n0 + lb_c;

    float acc[4][4] = {};
    for (int k0 = 0; k0 < K; k0 += 16) {
        float4 a4 = a_in ? *(const float4*)(Ap + k0) : make_float4(0.f,0.f,0.f,0.f);
        float4 b4 = *(const float4*)(Bp + (size_t)k0 * N);
        As[la_c+0][la_r] = a4.x; As[la_c+1][la_r] = a4.y;
        As[la_c+2][la_r] = a4.z; As[la_c+3][la_r] = a4.w;
        Bs[lb_r][lb_c+0] = b4.x; Bs[lb_r][lb_c+1] = b4.y;
        Bs[lb_r][lb_c+2] = b4.z; Bs[lb_r][lb_c+3] = b4.w;
        __syncthreads();
        #pragma unroll
        for (int kk = 0; kk < 16; ++kk) {
            float4 av = *(const float4*)&As[kk][tm];
            float4 bv = *(const float4*)&Bs[kk][tn];
            float a[4] = {av.x, av.y, av.z, av.w};
            float b[4] = {bv.x, bv.y, bv.z, bv.w};
            #pragma unroll
            for (int i = 0; i < 4; ++i)
                #pragma unroll
                for (int j = 0; j < 4; ++j)
                    acc[i][j] = fmaf(a[i], b[j], acc[i][j]);
        }
        __syncthreads();
    }

    float g = 1.f, og = 0.f;
    if (SKIP) { float s = *gatep; g = 1.f / (1.f + expf(-s)); og = 1.f - g; }
    #pragma unroll
    for (int i = 0; i < 4; ++i) {
        int m = m0 + tm + i;
        if (m >= M) continue;
        #pragma unroll
        for (int j = 0; j < 4; ++j) {
            int n = n0 + tn + j;
            float v = acc[i][j] + bias[n];
            if (ACT == 1) v = fmaxf(v, 0.f);
            if (SKIP) v = g * v + og * skipx[(size_t)m * N + n];
            C[(size_t)m * N + n] = v;
        }
    }
}

// ---------------- per-head 64x64 block-diagonal GEMM ----------------
// Y[n, h*64+e] = sum_d X[n, col_off + h*64 + d] * W[h, d, e]
__global__ __launch_bounds__(256) void blockdiag_gemm(
    const float* __restrict__ X, int ld_x, int col_off,
    const float* __restrict__ W,  // H x 64 x 64 (this relation)
    float* __restrict__ Y, int M)
{
    const int h  = blockIdx.y;
    const int m0 = blockIdx.x * 64;
    __shared__ __align__(16) float As[64][68];  // [d][m]
    __shared__ __align__(16) float Ws[64][68];  // [d][e]
    const int t = threadIdx.x;
    const float* Wh = W + (size_t)h * 4096;
    #pragma unroll
    for (int j = 0; j < 4; ++j) {
        int idx4 = t + 256 * j;
        int flat = idx4 * 4;
        int rr = flat >> 6, cc = flat & 63;
        float4 w4 = *(const float4*)(Wh + flat);
        Ws[rr][cc+0] = w4.x; Ws[rr][cc+1] = w4.y; Ws[rr][cc+2] = w4.z; Ws[rr][cc+3] = w4.w;
        int m = m0 + rr;
        float4 a4 = (m < M) ? *(const float4*)(X + (size_t)m * ld_x + col_off + h * 64 + cc)
                            : make_float4(0.f,0.f,0.f,0.f);
        As[cc+0][rr] = a4.x; As[cc+1][rr] = a4.y; As[cc+2][rr] = a4.z; As[cc+3][rr] = a4.w;
    }
    __syncthreads();
    const int tm = (t & 15) * 4, tn = (t >> 4) * 4;
    float acc[4][4] = {};
    #pragma unroll 8
    for (int k = 0; k < 64; ++k) {
        float4 av = *(const float4*)&As[k][tm];
        float4 bv = *(const float4*)&Ws[k][tn];
        float a[4] = {av.x, av.y, av.z, av.w};
        float b[4] = {bv.x, bv.y, bv.z, bv.w};
        #pragma unroll
        for (int i = 0; i < 4; ++i)
            #pragma unroll
            for (int j = 0; j < 4; ++j)
                acc[i][j] = fmaf(a[i], b[j], acc[i][j]);
    }
    #pragma unroll
    for (int i = 0; i < 4; ++i) {
        int m = m0 + tm + i;
        if (m >= M) continue;
        #pragma unroll
        for (int j = 0; j < 4; ++j)
            Y[(size_t)m * 512 + h * 64 + tn + j] = acc[i][j];
    }
}

// ---------------- alpha + segment-max (one relation) ----------------
// one wave per edge; lane covers 8 consecutive dims; head = lane/8
__global__ __launch_bounds__(256) void alpha_kernel(
    const float* __restrict__ krel, const float* __restrict__ kqv,
    const int* __restrict__ ei, const float* __restrict__ prel,
    int r, float* __restrict__ alpha, unsigned* __restrict__ amax)
{
    int gid  = blockIdx.x * 256 + threadIdx.x;
    int e    = gid >> 6;
    int lane = gid & 63;
    if (e >= EE) return;
    int src = ei[(size_t)r * 2 * EE + e];
    int dst = ei[(size_t)r * 2 * EE + EE + e];
    const float* kp = krel + (size_t)src * 512 + lane * 8;
    const float* qp = kqv  + (size_t)dst * 1536 + 512 + lane * 8;
    float4 k0 = *(const float4*)kp, k1 = *(const float4*)(kp + 4);
    float4 q0 = *(const float4*)qp, q1 = *(const float4*)(qp + 4);
    float s = k0.x*q0.x + k0.y*q0.y + k0.z*q0.z + k0.w*q0.w
            + k1.x*q1.x + k1.y*q1.y + k1.z*q1.z + k1.w*q1.w;
    s += __shfl_xor(s, 1);
    s += __shfl_xor(s, 2);
    s += __shfl_xor(s, 4);
    if ((lane & 7) == 0) {
        int h = lane >> 3;
        float a = s * prel[r * NH + h] * SCALEF;
        alpha[((size_t)r * EE + e) * NH + h] = a;
        atomicMax(&amax[(size_t)dst * NH + h], enc_f(a));
    }
}

__global__ void finalize_amax(unsigned* __restrict__ amax, float* __restrict__ amaxf, int n)
{
    int i = blockIdx.x * 256 + threadIdx.x;
    if (i < n) amaxf[i] = dec_f(amax[i]);
}

// ---------------- exp + segment-sum denominator (all edges) ----------------
__global__ void ae_kernel(float* __restrict__ alpha, const float* __restrict__ amaxf,
                          const int* __restrict__ ei, float* __restrict__ denom)
{
    int idx = blockIdx.x * 256 + threadIdx.x;
    if (idx >= MEDGE * NH) return;
    int h = idx & 7;
    int eflat = idx >> 3;
    int r = eflat / EE, e = eflat - r * EE;
    int dst = ei[(size_t)r * 2 * EE + EE + e];
    float a = alpha[idx];
    float v = expf(a - amaxf[(size_t)dst * 8 + h]);
    alpha[idx] = v;
    atomicAdd(&denom[(size_t)dst * 8 + h], v);
}

// ---------------- weighted aggregation (one relation) ----------------
__global__ __launch_bounds__(256) void agg_kernel(
    const float* __restrict__ vrel, const float* __restrict__ ae,
    const float* __restrict__ denom, const int* __restrict__ ei,
    int r, float* __restrict__ agg)
{
    int gid  = blockIdx.x * 256 + threadIdx.x;
    int e    = gid >> 6;
    int lane = gid & 63;
    if (e >= EE) return;
    int src = ei[(size_t)r * 2 * EE + e];
    int dst = ei[(size_t)r * 2 * EE + EE + e];
    int h = lane >> 3;
    float w = ae[((size_t)r * EE + e) * 8 + h] / (denom[(size_t)dst * 8 + h] + 1e-16f);
    const float* vp = vrel + (size_t)src * 512 + lane * 8;
    float4 v0 = *(const float4*)vp, v1 = *(const float4*)(vp + 4);
    float* ap = agg + (size_t)dst * 512 + lane * 8;
    atomicAdd(ap + 0, v0.x * w);
    atomicAdd(ap + 1, v0.y * w);
    atomicAdd(ap + 2, v0.z * w);
    atomicAdd(ap + 3, v0.w * w);
    atomicAdd(ap + 4, v1.x * w);
    atomicAdd(ap + 5, v1.y * w);
    atomicAdd(ap + 6, v1.z * w);
    atomicAdd(ap + 7, v1.w * w);
}

__global__ void gelu_kernel(float* __restrict__ x, int n4)
{
    int i = blockIdx.x * 256 + threadIdx.x;
    if (i >= n4) return;
    float4 v = ((float4*)x)[i];
    v.x = gelu_exact(v.x); v.y = gelu_exact(v.y);
    v.z = gelu_exact(v.z); v.w = gelu_exact(v.w);
    ((float4*)x)[i] = v;
}

extern "C" void kernel_launch(void* const* d_in, const int* in_sizes, int n_in,
                              void* d_out, int out_size, void* d_ws, size_t ws_size,
                              hipStream_t stream)
{
    const float* x    = (const float*)d_in[0];
    const int*   ei   = (const int*)d_in[1];
    const float* ea   = (const float*)d_in[2];
    const float* Wkqv[2] = {(const float*)d_in[3],  (const float*)d_in[10]};
    const float* bkqv[2] = {(const float*)d_in[4],  (const float*)d_in[11]};
    const float* Wk[2]   = {(const float*)d_in[5],  (const float*)d_in[12]};
    const float* Wv[2]   = {(const float*)d_in[6],  (const float*)d_in[13]};
    const float* prel[2] = {(const float*)d_in[7],  (const float*)d_in[14]};
    const float* Wout[2] = {(const float*)d_in[8],  (const float*)d_in[15]};
    const float* bout[2] = {(const float*)d_in[9],  (const float*)d_in[16]};
    const float* skip1 = (const float*)d_in[17];
    const float* Wfc   = (const float*)d_in[18];
    const float* bfc   = (const float*)d_in[19];
    const float* We1   = (const float*)d_in[20];
    const float* be1   = (const float*)d_in[21];
    const float* We2   = (const float*)d_in[22];
    const float* be2   = (const float*)d_in[23];

    if (ws_size < WS_FLOATS * sizeof(float)) return;  // insufficient scratch

    float* ws    = (float*)d_ws;
    float* kqv   = ws + OFF_KQV;
    float* h0    = ws + OFF_H0;
    float* h1    = ws + OFF_H1;    // overlays kqv (dead by then)
    float* eint  = ws + OFF_EINT;  // overlays kqv (dead by then)
    float* agg   = ws + OFF_AGG;
    float* tmp   = ws + OFF_TMP;
    float* alpha = ws + OFF_ALPHA;
    unsigned* amax = (unsigned*)(ws + OFF_AMAX);
    float* denom = ws + OFF_DEN;
    float* outf  = (float*)d_out;

    const dim3 blk(256);
    const int mtiles = (NN + 63) / 64;

    for (int l = 0; l < 2; ++l) {
        const float* xin = (l == 0) ? x : h0;
        int K = (l == 0) ? CIN : HIDW;

        // kqv = xin @ Wkqv + b
        gemm_f32<0,false><<<dim3(1536/64, mtiles), blk, 0, stream>>>(
            xin, Wkqv[l], bkqv[l], kqv, NN, 1536, K, nullptr, nullptr);

        hipMemsetAsync(amax,  0, (size_t)NN * NH * sizeof(unsigned), stream);
        hipMemsetAsync(denom, 0, (size_t)NN * NH * sizeof(float), stream);
        hipMemsetAsync(agg,   0, (size_t)NN * HIDW * sizeof(float), stream);

        // alpha + segment max, per relation
        for (int r = 0; r < RR; ++r) {
            blockdiag_gemm<<<dim3(mtiles, NH), blk, 0, stream>>>(
                kqv, 1536, 0, Wk[l] + (size_t)r * NH * 64 * 64, tmp, NN);
            alpha_kernel<<<EE/4, blk, 0, stream>>>(tmp, kqv, ei, prel[l], r, alpha, amax);
        }
        finalize_amax<<<(NN*NH + 255)/256, blk, 0, stream>>>(amax, (float*)amax, NN*NH);
        ae_kernel<<<(MEDGE*NH + 255)/256, blk, 0, stream>>>(alpha, (const float*)amax, ei, denom);

        // weighted aggregation, per relation
        for (int r = 0; r < RR; ++r) {
            blockdiag_gemm<<<dim3(mtiles, NH), blk, 0, stream>>>(
                kqv, 1536, 1024, Wv[l] + (size_t)r * NH * 64 * 64, tmp, NN);
            agg_kernel<<<EE/4, blk, 0, stream>>>(tmp, alpha, denom, ei, r, agg);
        }

        gelu_kernel<<<(NN*HIDW/4 + 255)/256, blk, 0, stream>>>(agg, NN*HIDW/4);

        if (l == 0) {
            gemm_f32<0,false><<<dim3(HIDW/64, mtiles), blk, 0, stream>>>(
                agg, Wout[0], bout[0], h0, NN, HIDW, HIDW, nullptr, nullptr);
        } else {
            gemm_f32<0,true><<<dim3(HIDW/64, mtiles), blk, 0, stream>>>(
                agg, Wout[1], bout[1], h1, NN, HIDW, HIDW, h0, skip1);
        }
    }

    // node_embeds = h1 @ Wfc + bfc
    gemm_f32<0,false><<<dim3(OUTW/64, mtiles), blk, 0, stream>>>(
        h1, Wfc, bfc, outf, NN, OUTW, HIDW, nullptr, nullptr);

    // edge_embeds = relu(e @ We1 + be1) @ We2 + be2, in 4 chunks of 40000 rows
    for (int c = 0; c < 4; ++c) {
        const float* ec = ea + (size_t)c * 40000 * CEDGE;
        gemm_f32<1,false><<<dim3(HIDW/64, 40000/64), blk, 0, stream>>>(
            ec, We1, be1, eint, 40000, HIDW, CEDGE, nullptr, nullptr);
        gemm_f32<0,false><<<dim3(OUTW/64, 40000/64), blk, 0, stream>>>(
            eint, We2, be2, outf + 5120000 + (size_t)c * 40000 * OUTW,
            40000, OUTW, 512, nullptr, nullptr);
    }
}

// Round 2
// 2752.618 us; speedup vs baseline: 2.5103x; 2.5103x over previous
//
#include <hip/hip_runtime.h>
#include <cstdint>
#include <cstddef>

#define NN      20000
#define RR      4
#define EE      40000
#define CIN     256
#define CEDGE   128
#define HIDW    512
#define OUTW    256
#define NH      8
#define DH      64
#define MEDGE   (RR*EE)
#define SCALEF  0.125f

// ---- ws layout (4-byte elements) ----
#define OFF_K     0ull            // k buffer; later: wsum buffer; later: edge-MLP interm (with Q)
#define OFF_Q     10240000ull     // q buffer; later: agg
#define OFF_V     20480000ull     // v buffer
#define OFF_TMP   30720000ull     // k_rel; later: h1
#define OFF_H0    40960000ull
#define OFF_ALPHA 51200000ull     // 160000*8
#define OFF_LSE   52480000ull     // 20000*8 floats; fill-counts (ints) during CSR build
#define OFF_ROWP  52640000ull     // 20001 ints
#define OFF_EREC  52660008ull     // 160000 ints
#define WS_NEED   52820008ull

__device__ __forceinline__ float gelu_exact(float x) {
    return 0.5f * x * (1.0f + erff(x * 0.70710678118654752f));
}

// ---------------- generic f32 GEMM: C = act(A@B + bias) [optional skip mix] ----------------
// A: M x K (lda), B: K x N slice (ldb), C: M x N (ldc). N%64==0, K%16==0. M guarded.
template<int ACT, bool SKIP>
__global__ __launch_bounds__(256) void gemm_f32(
    const float* __restrict__ A, int lda,
    const float* __restrict__ B, int ldb,
    const float* __restrict__ bias, float* __restrict__ C, int ldc,
    int M, int N, int K,
    const float* __restrict__ skipx, const float* __restrict__ gatep)
{
    __shared__ __align__(16) float As[16][68];  // [k][m]
    __shared__ __align__(16) float Bs[16][68];  // [k][n]
    const int t  = threadIdx.x;
    const int m0 = blockIdx.y * 64, n0 = blockIdx.x * 64;
    const int tm = (t & 15) * 4, tn = (t >> 4) * 4;
    const int la_r = t >> 2, la_c = (t & 3) * 4;   // A tile: 64 rows x 16 k
    const int lb_r = t >> 4, lb_c = (t & 15) * 4;  // B tile: 16 k x 64 cols
    const bool a_in = (m0 + la_r) < M;
    const float* Ap = A + (size_t)(m0 + la_r) * lda + la_c;
    const float* Bp = B + (size_t)lb_r * ldb + n0 + lb_c;

    float acc[4][4] = {};
    for (int k0 = 0; k0 < K; k0 += 16) {
        float4 a4 = a_in ? *(const float4*)(Ap + k0) : make_float4(0.f,0.f,0.f,0.f);
        float4 b4 = *(const float4*)(Bp + (size_t)k0 * ldb);
        As[la_c+0][la_r] = a4.x; As[la_c+1][la_r] = a4.y;
        As[la_c+2][la_r] = a4.z; As[la_c+3][la_r] = a4.w;
        Bs[lb_r][lb_c+0] = b4.x; Bs[lb_r][lb_c+1] = b4.y;
        Bs[lb_r][lb_c+2] = b4.z; Bs[lb_r][lb_c+3] = b4.w;
        __syncthreads();
        #pragma unroll
        for (int kk = 0; kk < 16; ++kk) {
            float4 av = *(const float4*)&As[kk][tm];
            float4 bv = *(const float4*)&Bs[kk][tn];
            float a[4] = {av.x, av.y, av.z, av.w};
            float b[4] = {bv.x, bv.y, bv.z, bv.w};
            #pragma unroll
            for (int i = 0; i < 4; ++i)
                #pragma unroll
                for (int j = 0; j < 4; ++j)
                    acc[i][j] = fmaf(a[i], b[j], acc[i][j]);
        }
        __syncthreads();
    }

    float g = 1.f, og = 0.f;
    if (SKIP) { float s = *gatep; g = 1.f / (1.f + expf(-s)); og = 1.f - g; }
    #pragma unroll
    for (int i = 0; i < 4; ++i) {
        int m = m0 + tm + i;
        if (m >= M) continue;
        #pragma unroll
        for (int j = 0; j < 4; ++j) {
            int n = n0 + tn + j;
            float v = acc[i][j] + bias[n];
            if (ACT == 1) v = fmaxf(v, 0.f);
            if (SKIP) v = g * v + og * skipx[(size_t)m * ldc + n];
            C[(size_t)m * ldc + n] = v;
        }
    }
}

// ---------------- per-head 64x64 block-diagonal GEMM (optionally accumulating) ----------------
// Y[n, h*64+e] (+)= sum_d X[n, h*64+d] * W[h, d, e]
template<bool ACC>
__global__ __launch_bounds__(256) void blockdiag_gemm(
    const float* __restrict__ X, int ldx,
    const float* __restrict__ W,  // H x 64 x 64 (this relation)
    float* __restrict__ Y, int ldy, int M)
{
    const int h  = blockIdx.y;
    const int m0 = blockIdx.x * 64;
    __shared__ __align__(16) float As[64][68];  // [d][m]
    __shared__ __align__(16) float Ws[64][68];  // [d][e]
    const int t = threadIdx.x;
    const float* Wh = W + (size_t)h * 4096;
    #pragma unroll
    for (int j = 0; j < 4; ++j) {
        int idx4 = t + 256 * j;
        int flat = idx4 * 4;
        int rr = flat >> 6, cc = flat & 63;
        float4 w4 = *(const float4*)(Wh + flat);
        Ws[rr][cc+0] = w4.x; Ws[rr][cc+1] = w4.y; Ws[rr][cc+2] = w4.z; Ws[rr][cc+3] = w4.w;
        int m = m0 + rr;
        float4 a4 = (m < M) ? *(const float4*)(X + (size_t)m * ldx + h * 64 + cc)
                            : make_float4(0.f,0.f,0.f,0.f);
        As[cc+0][rr] = a4.x; As[cc+1][rr] = a4.y; As[cc+2][rr] = a4.z; As[cc+3][rr] = a4.w;
    }
    __syncthreads();
    const int tm = (t & 15) * 4, tn = (t >> 4) * 4;
    float acc[4][4] = {};
    #pragma unroll 8
    for (int k = 0; k < 64; ++k) {
        float4 av = *(const float4*)&As[k][tm];
        float4 bv = *(const float4*)&Ws[k][tn];
        float a[4] = {av.x, av.y, av.z, av.w};
        float b[4] = {bv.x, bv.y, bv.z, bv.w};
        #pragma unroll
        for (int i = 0; i < 4; ++i)
            #pragma unroll
            for (int j = 0; j < 4; ++j)
                acc[i][j] = fmaf(a[i], b[j], acc[i][j]);
    }
    #pragma unroll
    for (int i = 0; i < 4; ++i) {
        int m = m0 + tm + i;
        if (m >= M) continue;
        #pragma unroll
        for (int j = 0; j < 4; ++j) {
            float* yp = &Y[(size_t)m * ldy + h * 64 + tn + j];
            if (ACC) *yp += acc[i][j]; else *yp = acc[i][j];
        }
    }
}

// ---------------- CSR build (edges identical for both layers) ----------------
__global__ void deg_kernel(const int* __restrict__ ei, int* __restrict__ rowptr)
{
    int idx = blockIdx.x * 256 + threadIdx.x;
    if (idx >= MEDGE) return;
    int r = idx / EE;
    int dst = ei[idx + (r + 1) * EE];
    atomicAdd(&rowptr[dst], 1);
}

__global__ __launch_bounds__(256) void scan_kernel(int* __restrict__ rowptr)
{
    __shared__ int buf[256];
    __shared__ int carry;
    const int t = threadIdx.x;
    if (t == 0) carry = 0;
    __syncthreads();
    for (int base = 0; base < NN; base += 256) {
        int i = base + t;
        int v = (i < NN) ? rowptr[i] : 0;
        buf[t] = v;
        __syncthreads();
        for (int off = 1; off < 256; off <<= 1) {
            int tv = (t >= off) ? buf[t - off] : 0;
            __syncthreads();
            buf[t] += tv;
            __syncthreads();
        }
        int total = buf[255];
        int excl = buf[t] - v;
        int c = carry;
        __syncthreads();
        if (i < NN) rowptr[i] = c + excl;
        if (t == 0) carry = c + total;
        __syncthreads();
    }
    if (t == 0) rowptr[NN] = carry;
}

__global__ void fill_kernel(const int* __restrict__ ei, const int* __restrict__ rowptr,
                            int* __restrict__ fillcnt, int* __restrict__ erec)
{
    int idx = blockIdx.x * 256 + threadIdx.x;
    if (idx >= MEDGE) return;
    int r = idx / EE;
    int dst = ei[idx + (r + 1) * EE];
    int pos = rowptr[dst] + atomicAdd(&fillcnt[dst], 1);
    erec[pos] = idx;
}

// ---------------- alpha (one relation, no atomics) ----------------
// one wave per edge; lane covers 8 consecutive dims; head = lane/8
__global__ __launch_bounds__(256) void alpha_kernel(
    const float* __restrict__ krel, const float* __restrict__ q,
    const int* __restrict__ ei, const float* __restrict__ prel,
    int r, float* __restrict__ alpha)
{
    int gid  = blockIdx.x * 256 + threadIdx.x;
    int e    = gid >> 6;
    int lane = gid & 63;
    if (e >= EE) return;
    int src = ei[(size_t)r * 2 * EE + e];
    int dst = ei[(size_t)r * 2 * EE + EE + e];
    const float* kp = krel + (size_t)src * 512 + lane * 8;
    const float* qp = q    + (size_t)dst * 512 + lane * 8;
    float4 k0 = *(const float4*)kp, k1 = *(const float4*)(kp + 4);
    float4 q0 = *(const float4*)qp, q1 = *(const float4*)(qp + 4);
    float s = k0.x*q0.x + k0.y*q0.y + k0.z*q0.z + k0.w*q0.w
            + k1.x*q1.x + k1.y*q1.y + k1.z*q1.z + k1.w*q1.w;
    s += __shfl_xor(s, 1);
    s += __shfl_xor(s, 2);
    s += __shfl_xor(s, 4);
    if ((lane & 7) == 0) {
        int h = lane >> 3;
        alpha[((size_t)r * EE + e) * NH + h] = s * prel[r * NH + h] * SCALEF;
    }
}

// ---------------- softmax stats: lse[n,h] = max + log(sum exp) (wave per node) ----------------
__global__ __launch_bounds__(256) void softmax_stats(
    const float* __restrict__ alpha, const int* __restrict__ rowptr,
    const int* __restrict__ erec, float* __restrict__ lse)
{
    int n    = (blockIdx.x * 256 + threadIdx.x) >> 6;
    int lane = threadIdx.x & 63;
    if (n >= NN) return;
    int p0 = rowptr[n], p1 = rowptr[n + 1];
    int h = lane & 7, es = lane >> 3;
    float m = -3.0e38f;
    for (int j = p0 + es; j < p1; j += 8) {
        int idx = erec[j];
        m = fmaxf(m, alpha[(size_t)idx * 8 + h]);
    }
    m = fmaxf(m, __shfl_xor(m, 8));
    m = fmaxf(m, __shfl_xor(m, 16));
    m = fmaxf(m, __shfl_xor(m, 32));
    float s = 0.f;
    for (int j = p0 + es; j < p1; j += 8) {
        int idx = erec[j];
        s += expf(alpha[(size_t)idx * 8 + h] - m);
    }
    s += __shfl_xor(s, 8);
    s += __shfl_xor(s, 16);
    s += __shfl_xor(s, 32);
    if (lane < 8) lse[(size_t)n * 8 + lane] = m + logf(s + 1e-16f);
}

// ---------------- weighted v aggregation (one relation, wave per node, no atomics) ----------------
__global__ __launch_bounds__(256) void wsum_kernel(
    const float* __restrict__ v, const float* __restrict__ alpha,
    const float* __restrict__ lse, const int* __restrict__ rowptr,
    const int* __restrict__ erec, const int* __restrict__ ei,
    int r, float* __restrict__ out)
{
    int n    = (blockIdx.x * 256 + threadIdx.x) >> 6;
    int lane = threadIdx.x & 63;
    if (n >= NN) return;
    int p0 = rowptr[n], p1 = rowptr[n + 1];
    int h = lane >> 3;
    int lo = r * EE, hi = lo + EE;
    float ls = lse[(size_t)n * 8 + h];
    float acc0=0,acc1=0,acc2=0,acc3=0,acc4=0,acc5=0,acc6=0,acc7=0;
    for (int j = p0; j < p1; ++j) {
        int idx = erec[j];
        if (idx < lo || idx >= hi) continue;
        int src = ei[idx + r * EE];
        float w = expf(alpha[(size_t)idx * 8 + h] - ls);
        const float* vp = v + (size_t)src * 512 + lane * 8;
        float4 a4 = *(const float4*)vp, b4 = *(const float4*)(vp + 4);
        acc0 += w * a4.x; acc1 += w * a4.y; acc2 += w * a4.z; acc3 += w * a4.w;
        acc4 += w * b4.x; acc5 += w * b4.y; acc6 += w * b4.z; acc7 += w * b4.w;
    }
    float* op = out + (size_t)n * 512 + lane * 8;
    *(float4*)op       = make_float4(acc0, acc1, acc2, acc3);
    *(float4*)(op + 4) = make_float4(acc4, acc5, acc6, acc7);
}

__global__ void gelu_kernel(float* __restrict__ x, int n4)
{
    int i = blockIdx.x * 256 + threadIdx.x;
    if (i >= n4) return;
    float4 v = ((float4*)x)[i];
    v.x = gelu_exact(v.x); v.y = gelu_exact(v.y);
    v.z = gelu_exact(v.z); v.w = gelu_exact(v.w);
    ((float4*)x)[i] = v;
}

extern "C" void kernel_launch(void* const* d_in, const int* in_sizes, int n_in,
                              void* d_out, int out_size, void* d_ws, size_t ws_size,
                              hipStream_t stream)
{
    const float* x    = (const float*)d_in[0];
    const int*   ei   = (const int*)d_in[1];
    const float* ea   = (const float*)d_in[2];
    const float* Wkqv[2] = {(const float*)d_in[3],  (const float*)d_in[10]};
    const float* bkqv[2] = {(const float*)d_in[4],  (const float*)d_in[11]};
    const float* Wk[2]   = {(const float*)d_in[5],  (const float*)d_in[12]};
    const float* Wv[2]   = {(const float*)d_in[6],  (const float*)d_in[13]};
    const float* prel[2] = {(const float*)d_in[7],  (const float*)d_in[14]};
    const float* Wout[2] = {(const float*)d_in[8],  (const float*)d_in[15]};
    const float* bout[2] = {(const float*)d_in[9],  (const float*)d_in[16]};
    const float* skip1 = (const float*)d_in[17];
    const float* Wfc   = (const float*)d_in[18];
    const float* bfc   = (const float*)d_in[19];
    const float* We1   = (const float*)d_in[20];
    const float* be1   = (const float*)d_in[21];
    const float* We2   = (const float*)d_in[22];
    const float* be2   = (const float*)d_in[23];

    if (ws_size < WS_NEED * 4) return;

    float* ws      = (float*)d_ws;
    float* kbuf    = ws + OFF_K;
    float* qbuf    = ws + OFF_Q;
    float* vbuf    = ws + OFF_V;
    float* tmp     = ws + OFF_TMP;
    float* h0      = ws + OFF_H0;
    float* alpha   = ws + OFF_ALPHA;
    float* lse     = ws + OFF_LSE;
    int*   fillcnt = (int*)(ws + OFF_LSE);   // build-time overlay
    int*   rowptr  = (int*)(ws + OFF_ROWP);
    int*   erec    = (int*)(ws + OFF_EREC);
    float* wsumbuf = kbuf;                   // k dead by aggregation time
    float* agg     = qbuf;                   // q dead by aggregation time
    float* h1      = tmp;                    // tmp dead after layer 1
    float* eint    = kbuf;                   // k+q regions (20.48M) dead at edge phase
    float* outf    = (float*)d_out;

    const dim3 blk(256);
    const int mtiles = (NN + 63) / 64;
    const int ntiles_node = mtiles;

    // ---- CSR build (once; edges shared by both layers) ----
    hipMemsetAsync(rowptr, 0, (NN + 1) * sizeof(int), stream);
    hipMemsetAsync(fillcnt, 0, NN * sizeof(int), stream);
    deg_kernel<<<(MEDGE + 255) / 256, blk, 0, stream>>>(ei, rowptr);
    scan_kernel<<<1, blk, 0, stream>>>(rowptr);
    fill_kernel<<<(MEDGE + 255) / 256, blk, 0, stream>>>(ei, rowptr, fillcnt, erec);

    for (int l = 0; l < 2; ++l) {
        const float* xin = (l == 0) ? x : h0;
        int K = (l == 0) ? CIN : HIDW;

        // k,q,v = xin @ Wkqv slices + b
        gemm_f32<0,false><<<dim3(8, mtiles), blk, 0, stream>>>(
            xin, K, Wkqv[l] + 0,    1536, bkqv[l] + 0,    kbuf, 512, NN, 512, K, nullptr, nullptr);
        gemm_f32<0,false><<<dim3(8, mtiles), blk, 0, stream>>>(
            xin, K, Wkqv[l] + 512,  1536, bkqv[l] + 512,  qbuf, 512, NN, 512, K, nullptr, nullptr);
        gemm_f32<0,false><<<dim3(8, mtiles), blk, 0, stream>>>(
            xin, K, Wkqv[l] + 1024, 1536, bkqv[l] + 1024, vbuf, 512, NN, 512, K, nullptr, nullptr);

        // alpha per relation (k_rel in tmp)
        for (int r = 0; r < RR; ++r) {
            blockdiag_gemm<false><<<dim3(ntiles_node, NH), blk, 0, stream>>>(
                kbuf, 512, Wk[l] + (size_t)r * NH * 4096, tmp, 512, NN);
            alpha_kernel<<<EE / 4, blk, 0, stream>>>(tmp, qbuf, ei, prel[l], r, alpha);
        }

        softmax_stats<<<(NN * 64) / 256, blk, 0, stream>>>(alpha, rowptr, erec, lse);

        // weighted aggregation + per-relation Wv transform (accumulate into agg)
        for (int r = 0; r < RR; ++r) {
            wsum_kernel<<<(NN * 64) / 256, blk, 0, stream>>>(
                vbuf, alpha, lse, rowptr, erec, ei, r, wsumbuf);
            if (r == 0)
                blockdiag_gemm<false><<<dim3(ntiles_node, NH), blk, 0, stream>>>(
                    wsumbuf, 512, Wv[l] + (size_t)r * NH * 4096, agg, 512, NN);
            else
                blockdiag_gemm<true><<<dim3(ntiles_node, NH), blk, 0, stream>>>(
                    wsumbuf, 512, Wv[l] + (size_t)r * NH * 4096, agg, 512, NN);
        }

        gelu_kernel<<<(NN * HIDW / 4 + 255) / 256, blk, 0, stream>>>(agg, NN * HIDW / 4);

        if (l == 0) {
            gemm_f32<0,false><<<dim3(8, mtiles), blk, 0, stream>>>(
                agg, 512, Wout[0], 512, bout[0], h0, 512, NN, 512, 512, nullptr, nullptr);
        } else {
            gemm_f32<0,true><<<dim3(8, mtiles), blk, 0, stream>>>(
                agg, 512, Wout[1], 512, bout[1], h1, 512, NN, 512, 512, h0, skip1);
        }
    }

    // node_embeds = h1 @ Wfc + bfc
    gemm_f32<0,false><<<dim3(4, mtiles), blk, 0, stream>>>(
        h1, 512, Wfc, 256, bfc, outf, 256, NN, 256, 512, nullptr, nullptr);

    // edge_embeds = relu(e @ We1 + be1) @ We2 + be2, in 4 chunks of 40000 rows
    for (int c = 0; c < 4; ++c) {
        const float* ec = ea + (size_t)c * 40000 * CEDGE;
        gemm_f32<1,false><<<dim3(8, 625), blk, 0, stream>>>(
            ec, 128, We1, 512, be1, eint, 512, 40000, 512, 128, nullptr, nullptr);
        gemm_f32<0,false><<<dim3(4, 625), blk, 0, stream>>>(
            eint, 512, We2, 256, be2, outf + 5120000 + (size_t)c * 40000 * OUTW, 256,
            40000, 256, 512, nullptr, nullptr);
    }
}

// Round 3
// 1042.952 us; speedup vs baseline: 6.6252x; 2.6393x over previous
//
#include <hip/hip_runtime.h>
#include <cstdint>
#include <cstddef>

#define NN      20000
#define RR      4
#define EE      40000
#define CIN     256
#define CEDGE   128
#define HIDW    512
#define OUTW    256
#define NH      8
#define MEDGE   (RR*EE)
#define SCALEF  0.125f

typedef unsigned short u16;
typedef short s8v  __attribute__((ext_vector_type(8)));
typedef float f32x4 __attribute__((ext_vector_type(4)));

// ---- ws layout (BYTE offsets) ----
#define B_XB    0ull                    // 20000*256*2  = 10,240,000
#define B_KQV   10240000ull             // 20000*1536*2 = 61,440,000
#define B_KREL  71680000ull             // 8*20000*256*2 = 81,920,000 (wsumH overlays after alpha)
#define B_AGG   153600000ull            // 20000*512*2
#define B_H0    174080000ull            // 20000*512*2
#define B_H1    194560000ull            // 20000*512*2
#define B_ALPHA 215040000ull            // 160000*8*4 = 5,120,000 (f32)
#define B_LSE   220160000ull            // 20000*8*4 (f32); fillcnt overlay during CSR build
#define B_ROWP  220800000ull            // 20001*4 -> pad
#define B_EREC  220880128ull            // 160000*4
#define B_WTS   221520128ull            // bf16 weights, ~5.2 MB
// edge-phase overlays (node buffers dead):
#define B_EAB   0ull                    // 40000*128*2 = 10,240,000 per chunk
#define B_EINT  10240000ull             // 40000*512*2 = 40,960,000 per chunk
#define WS_NEED 227000000ull

#define SZH ((size_t)NN * 256)          // elements per head-matrix (krelH / wsumH)

__device__ __forceinline__ u16 f2b(float f) {
    unsigned u = __float_as_uint(f);
    unsigned r = (u + 0x7FFFu + ((u >> 16) & 1u)) >> 16;
    return (u16)r;
}
__device__ __forceinline__ float b2f(u16 h) { return __uint_as_float(((unsigned)h) << 16); }
__device__ __forceinline__ float gelu_exact(float x) {
    return 0.5f * x * (1.0f + erff(x * 0.70710678118654752f));
}

// =============== generic bf16 MFMA GEMM ===============
// A: M x K bf16 row-major (lda), BT: N x K bf16 row-major (ldb), C: M x N (ldc).
// batched over blockIdx.z via element strides. K%64==0, N%BN==0. M guarded (rows clamped on load).
// ACT: 0 none, 1 relu, 2 gelu. SKIP: out = g*out+(1-g)*skipx (bf16).
template<int BN, int ACT, bool OUTBF16, bool BIAS, bool SKIP>
__global__ __launch_bounds__(256) void gemm_bf16(
    const u16* __restrict__ A, int lda, size_t astride,
    const u16* __restrict__ BT, int ldb, size_t bstride,
    const float* __restrict__ bias,
    void* __restrict__ Cv, int ldc, size_t cstride,
    int M, int K,
    const u16* __restrict__ skipx, const float* __restrict__ gatep)
{
    constexpr int FN  = BN / 32;        // frags per wave along N (wave covers BN/2)
    constexpr int NBI = BN / 32;        // B staging chunks per thread
    __shared__ __align__(16) u16 As[128 * 72];
    __shared__ __align__(16) u16 Bs[BN * 72];

    const int t = threadIdx.x, lane = t & 63, wid = t >> 6;
    const int m0 = blockIdx.y * 128, n0 = blockIdx.x * BN;
    const int z  = blockIdx.z;
    A  += (size_t)z * astride;
    BT += (size_t)z * bstride;
    const int wm = wid >> 1, wn = wid & 1;

    f32x4 acc[4][FN];
    #pragma unroll
    for (int i = 0; i < 4; ++i)
        #pragma unroll
        for (int j = 0; j < FN; ++j)
            acc[i][j] = (f32x4){0.f, 0.f, 0.f, 0.f};

    for (int k0 = 0; k0 < K; k0 += 64) {
        #pragma unroll
        for (int i = 0; i < 4; ++i) {               // A: 128 rows x 8 chunks
            int c = i * 256 + t;
            int row = c >> 3, cc = c & 7;
            int gr = m0 + row; gr = gr < M ? gr : M - 1;
            s8v v = *(const s8v*)(A + (size_t)gr * lda + k0 + cc * 8);
            *(s8v*)&As[row * 72 + cc * 8] = v;
        }
        #pragma unroll
        for (int i = 0; i < NBI; ++i) {             // B: BN rows x 8 chunks
            int c = i * 256 + t;
            int col = c >> 3, cc = c & 7;
            s8v v = *(const s8v*)(BT + (size_t)(n0 + col) * ldb + k0 + cc * 8);
            *(s8v*)&Bs[col * 72 + cc * 8] = v;
        }
        __syncthreads();
        #pragma unroll
        for (int ks = 0; ks < 2; ++ks) {
            s8v af[4], bf[FN];
            #pragma unroll
            for (int i = 0; i < 4; ++i)
                af[i] = *(const s8v*)&As[(wm * 64 + i * 16 + (lane & 15)) * 72 + ks * 32 + (lane >> 4) * 8];
            #pragma unroll
            for (int j = 0; j < FN; ++j)
                bf[j] = *(const s8v*)&Bs[(wn * (BN / 2) + j * 16 + (lane & 15)) * 72 + ks * 32 + (lane >> 4) * 8];
            #pragma unroll
            for (int i = 0; i < 4; ++i)
                #pragma unroll
                for (int j = 0; j < FN; ++j)
                    acc[i][j] = __builtin_amdgcn_mfma_f32_16x16x32_bf16(af[i], bf[j], acc[i][j], 0, 0, 0);
        }
        __syncthreads();
    }

    float gate = 1.f, ogate = 0.f;
    if (SKIP) { float s = *gatep; gate = 1.f / (1.f + expf(-s)); ogate = 1.f - gate; }
    u16*   Cb = (u16*)Cv   + (size_t)z * cstride;
    float* Cf = (float*)Cv + (size_t)z * cstride;
    #pragma unroll
    for (int i = 0; i < 4; ++i) {
        int rbase = m0 + wm * 64 + i * 16 + (lane >> 4) * 4;
        #pragma unroll
        for (int j = 0; j < FN; ++j) {
            int col = n0 + wn * (BN / 2) + j * 16 + (lane & 15);
            float bv = BIAS ? bias[col] : 0.f;
            #pragma unroll
            for (int q = 0; q < 4; ++q) {
                int r = rbase + q;
                if (r >= M) continue;
                float v = acc[i][j][q] + bv;
                if (ACT == 1) v = fmaxf(v, 0.f);
                if (ACT == 2) v = gelu_exact(v);
                if (SKIP) v = gate * v + ogate * b2f(skipx[(size_t)r * ldc + col]);
                if (OUTBF16) Cb[(size_t)r * ldc + col] = f2b(v);
                else         Cf[(size_t)r * ldc + col] = v;
            }
        }
    }
}

// =============== conversions ===============
__global__ void f2b_vec(const float* __restrict__ in, u16* __restrict__ out, int n8)
{
    int i = blockIdx.x * 256 + threadIdx.x;
    if (i >= n8) return;
    float4 a = ((const float4*)in)[i * 2 + 0];
    float4 b = ((const float4*)in)[i * 2 + 1];
    s8v r;
    r[0] = (short)f2b(a.x); r[1] = (short)f2b(a.y); r[2] = (short)f2b(a.z); r[3] = (short)f2b(a.w);
    r[4] = (short)f2b(b.x); r[5] = (short)f2b(b.y); r[6] = (short)f2b(b.z); r[7] = (short)f2b(b.w);
    ((s8v*)out)[i] = r;
}

// W [K x N] f32 -> WT [N x K] bf16
__global__ __launch_bounds__(256) void transpose_f2b(
    const float* __restrict__ W, u16* __restrict__ WT, int K, int N)
{
    __shared__ float tile[32][33];
    int kb = blockIdx.x * 32, nb = blockIdx.y * 32;
    int tx = threadIdx.x & 31, ty = threadIdx.x >> 5;   // ty 0..7
    #pragma unroll
    for (int i = 0; i < 32; i += 8)
        tile[ty + i][tx] = W[(size_t)(kb + ty + i) * N + nb + tx];
    __syncthreads();
    #pragma unroll
    for (int i = 0; i < 32; i += 8)
        WT[(size_t)(nb + ty + i) * K + kb + tx] = f2b(tile[tx][ty + i]);
}

// Wk[r][h][d][e] -> WkT[h][r*64+e][d]
__global__ void conv_wk(const float* __restrict__ Wk, u16* __restrict__ WkT)
{
    int idx = blockIdx.x * 256 + threadIdx.x;
    if (idx >= 8 * 256 * 64) return;
    int d = idx & 63, re = (idx >> 6) & 255, h = idx >> 14;
    int e = re & 63, r = re >> 6;
    WkT[idx] = f2b(Wk[(size_t)(((r * 8 + h) * 64 + d) * 64) + e]);
}

// Wv[r][h][d][e] -> WvT[h][e][r*64+d]
__global__ void conv_wv(const float* __restrict__ Wv, u16* __restrict__ WvT)
{
    int idx = blockIdx.x * 256 + threadIdx.x;
    if (idx >= 8 * 64 * 256) return;
    int d = idx & 63, r = (idx >> 6) & 3, e = (idx >> 8) & 63, h = idx >> 14;
    WvT[idx] = f2b(Wv[(size_t)(((r * 8 + h) * 64 + d) * 64) + e]);
}

// =============== CSR build ===============
__global__ void deg_kernel(const int* __restrict__ ei, int* __restrict__ rowptr)
{
    int idx = blockIdx.x * 256 + threadIdx.x;
    if (idx >= MEDGE) return;
    int r = idx / EE;
    atomicAdd(&rowptr[ei[idx + (r + 1) * EE]], 1);
}

__global__ __launch_bounds__(256) void scan_kernel(int* __restrict__ rowptr)
{
    __shared__ int buf[256];
    __shared__ int carry;
    const int t = threadIdx.x;
    if (t == 0) carry = 0;
    __syncthreads();
    for (int base = 0; base < NN; base += 256) {
        int i = base + t;
        int v = (i < NN) ? rowptr[i] : 0;
        buf[t] = v;
        __syncthreads();
        for (int off = 1; off < 256; off <<= 1) {
            int tv = (t >= off) ? buf[t - off] : 0;
            __syncthreads();
            buf[t] += tv;
            __syncthreads();
        }
        int total = buf[255];
        int excl = buf[t] - v;
        int c = carry;
        __syncthreads();
        if (i < NN) rowptr[i] = c + excl;
        if (t == 0) carry = c + total;
        __syncthreads();
    }
    if (t == 0) rowptr[NN] = carry;
}

__global__ void fill_kernel(const int* __restrict__ ei, const int* __restrict__ rowptr,
                            int* __restrict__ fillcnt, int* __restrict__ erec)
{
    int idx = blockIdx.x * 256 + threadIdx.x;
    if (idx >= MEDGE) return;
    int r = idx / EE;
    int dst = ei[idx + (r + 1) * EE];
    int pos = rowptr[dst] + atomicAdd(&fillcnt[dst], 1);
    erec[pos] = idx;
}

// =============== alpha (one relation; bf16 gathers, f32 dot) ===============
__global__ __launch_bounds__(256) void alpha_kernel(
    const u16* __restrict__ krelH, const u16* __restrict__ kqvb,
    const int* __restrict__ ei, const float* __restrict__ prel,
    int r, float* __restrict__ alpha)
{
    int gid  = blockIdx.x * 256 + threadIdx.x;
    int e    = gid >> 6;
    int lane = gid & 63;
    if (e >= EE) return;
    int src = ei[(size_t)r * 2 * EE + e];
    int dst = ei[(size_t)r * 2 * EE + EE + e];
    int h = lane >> 3, sub = lane & 7;
    const u16* kp = krelH + (size_t)h * SZH + (size_t)src * 256 + r * 64 + sub * 8;
    const u16* qp = kqvb + (size_t)dst * 1536 + 512 + h * 64 + sub * 8;
    s8v kv = *(const s8v*)kp;
    s8v qv = *(const s8v*)qp;
    float s = 0.f;
    #pragma unroll
    for (int j = 0; j < 8; ++j)
        s += b2f((u16)kv[j]) * b2f((u16)qv[j]);
    s += __shfl_xor(s, 1);
    s += __shfl_xor(s, 2);
    s += __shfl_xor(s, 4);
    if (sub == 0)
        alpha[((size_t)r * EE + e) * NH + h] = s * prel[r * NH + h] * SCALEF;
}

// =============== softmax stats: lse = max + log(sum exp) (wave per node) ===============
__global__ __launch_bounds__(256) void softmax_stats(
    const float* __restrict__ alpha, const int* __restrict__ rowptr,
    const int* __restrict__ erec, float* __restrict__ lse)
{
    int n    = (blockIdx.x * 256 + threadIdx.x) >> 6;
    int lane = threadIdx.x & 63;
    if (n >= NN) return;
    int p0 = rowptr[n], p1 = rowptr[n + 1];
    int h = lane & 7, es = lane >> 3;
    float m = -3.0e38f;
    for (int j = p0 + es; j < p1; j += 8)
        m = fmaxf(m, alpha[(size_t)erec[j] * 8 + h]);
    m = fmaxf(m, __shfl_xor(m, 8));
    m = fmaxf(m, __shfl_xor(m, 16));
    m = fmaxf(m, __shfl_xor(m, 32));
    float s = 0.f;
    for (int j = p0 + es; j < p1; j += 8)
        s += expf(alpha[(size_t)erec[j] * 8 + h] - m);
    s += __shfl_xor(s, 8);
    s += __shfl_xor(s, 16);
    s += __shfl_xor(s, 32);
    if (lane < 8) lse[(size_t)n * 8 + lane] = m + logf(s + 1e-16f);
}

// =============== weighted v aggregation (one relation; wave per node) ===============
// writes wsumH[h][n][r*64 + d] bf16
__global__ __launch_bounds__(256) void wsum_kernel(
    const u16* __restrict__ kqvb, const float* __restrict__ alpha,
    const float* __restrict__ lse, const int* __restrict__ rowptr,
    const int* __restrict__ erec, const int* __restrict__ ei,
    int r, u16* __restrict__ wsumH)
{
    int n    = (blockIdx.x * 256 + threadIdx.x) >> 6;
    int lane = threadIdx.x & 63;
    if (n >= NN) return;
    int p0 = rowptr[n], p1 = rowptr[n + 1];
    int h = lane >> 3;
    int lo = r * EE, hi = lo + EE;
    float ls = lse[(size_t)n * 8 + h];
    float acc[8] = {};
    for (int j = p0; j < p1; ++j) {
        int idx = erec[j];
        if (idx < lo || idx >= hi) continue;
        int src = ei[idx + r * EE];
        float w = expf(alpha[(size_t)idx * 8 + h] - ls);
        s8v vv = *(const s8v*)(kqvb + (size_t)src * 1536 + 1024 + lane * 8);
        #pragma unroll
        for (int q = 0; q < 8; ++q)
            acc[q] += w * b2f((u16)vv[q]);
    }
    s8v out;
    #pragma unroll
    for (int q = 0; q < 8; ++q) out[q] = (short)f2b(acc[q]);
    *(s8v*)(wsumH + (size_t)h * SZH + (size_t)n * 256 + r * 64 + (lane & 7) * 8) = out;
}

extern "C" void kernel_launch(void* const* d_in, const int* in_sizes, int n_in,
                              void* d_out, int out_size, void* d_ws, size_t ws_size,
                              hipStream_t stream)
{
    const float* x    = (const float*)d_in[0];
    const int*   ei   = (const int*)d_in[1];
    const float* ea   = (const float*)d_in[2];
    const float* Wkqv[2] = {(const float*)d_in[3],  (const float*)d_in[10]};
    const float* bkqv[2] = {(const float*)d_in[4],  (const float*)d_in[11]};
    const float* Wk[2]   = {(const float*)d_in[5],  (const float*)d_in[12]};
    const float* Wv[2]   = {(const float*)d_in[6],  (const float*)d_in[13]};
    const float* prel[2] = {(const float*)d_in[7],  (const float*)d_in[14]};
    const float* Wout[2] = {(const float*)d_in[8],  (const float*)d_in[15]};
    const float* bout[2] = {(const float*)d_in[9],  (const float*)d_in[16]};
    const float* skip1 = (const float*)d_in[17];
    const float* Wfc   = (const float*)d_in[18];
    const float* bfc   = (const float*)d_in[19];
    const float* We1   = (const float*)d_in[20];
    const float* be1   = (const float*)d_in[21];
    const float* We2   = (const float*)d_in[22];
    const float* be2   = (const float*)d_in[23];

    if (ws_size < WS_NEED) return;

    char* wsb = (char*)d_ws;
    u16*   xb    = (u16*)(wsb + B_XB);
    u16*   kqvb  = (u16*)(wsb + B_KQV);
    u16*   krelH = (u16*)(wsb + B_KREL);
    u16*   wsumH = krelH;                    // overlay (krel dead after alpha)
    u16*   aggb  = (u16*)(wsb + B_AGG);
    u16*   h0b   = (u16*)(wsb + B_H0);
    u16*   h1b   = (u16*)(wsb + B_H1);
    float* alpha = (float*)(wsb + B_ALPHA);
    float* lse   = (float*)(wsb + B_LSE);
    int*   fillcnt = (int*)(wsb + B_LSE);    // build-time overlay
    int*   rowptr  = (int*)(wsb + B_ROWP);
    int*   erec    = (int*)(wsb + B_EREC);
    u16*   eab   = (u16*)(wsb + B_EAB);
    u16*   eintb = (u16*)(wsb + B_EINT);
    float* outf  = (float*)d_out;

    // bf16 weight arena
    u16* wt = (u16*)(wsb + B_WTS);
    u16* WkqvT[2] = {wt, wt + 393216};              wt += 393216 + 786432;
    u16* WkT[2]   = {wt, wt + 131072};              wt += 262144;
    u16* WvT[2]   = {wt, wt + 131072};              wt += 262144;
    u16* WoutT[2] = {wt, wt + 262144};              wt += 524288;
    u16* WfcT     = wt;                             wt += 131072;
    u16* We1T     = wt;                             wt += 65536;
    u16* We2T     = wt;

    const dim3 blk(256);
    const int mt128  = (NN + 127) / 128;   // 157
    const int mt128e = (EE + 127) / 128;   // 313

    // ---- conversions ----
    f2b_vec<<<(NN * CIN / 8 + 255) / 256, blk, 0, stream>>>(x, xb, NN * CIN / 8);
    transpose_f2b<<<dim3(CIN / 32, 1536 / 32), blk, 0, stream>>>(Wkqv[0], WkqvT[0], CIN, 1536);
    transpose_f2b<<<dim3(HIDW / 32, 1536 / 32), blk, 0, stream>>>(Wkqv[1], WkqvT[1], HIDW, 1536);
    transpose_f2b<<<dim3(HIDW / 32, HIDW / 32), blk, 0, stream>>>(Wout[0], WoutT[0], HIDW, HIDW);
    transpose_f2b<<<dim3(HIDW / 32, HIDW / 32), blk, 0, stream>>>(Wout[1], WoutT[1], HIDW, HIDW);
    transpose_f2b<<<dim3(HIDW / 32, OUTW / 32), blk, 0, stream>>>(Wfc, WfcT, HIDW, OUTW);
    transpose_f2b<<<dim3(CEDGE / 32, HIDW / 32), blk, 0, stream>>>(We1, We1T, CEDGE, HIDW);
    transpose_f2b<<<dim3(HIDW / 32, OUTW / 32), blk, 0, stream>>>(We2, We2T, HIDW, OUTW);
    for (int l = 0; l < 2; ++l) {
        conv_wk<<<(131072 + 255) / 256, blk, 0, stream>>>(Wk[l], WkT[l]);
        conv_wv<<<(131072 + 255) / 256, blk, 0, stream>>>(Wv[l], WvT[l]);
    }

    // ---- CSR build ----
    hipMemsetAsync(rowptr, 0, (NN + 1) * sizeof(int), stream);
    hipMemsetAsync(fillcnt, 0, NN * sizeof(int), stream);
    deg_kernel<<<(MEDGE + 255) / 256, blk, 0, stream>>>(ei, rowptr);
    scan_kernel<<<1, blk, 0, stream>>>(rowptr);
    fill_kernel<<<(MEDGE + 255) / 256, blk, 0, stream>>>(ei, rowptr, fillcnt, erec);

    for (int l = 0; l < 2; ++l) {
        const u16* xin = (l == 0) ? xb : h0b;
        int K = (l == 0) ? CIN : HIDW;

        // kqv = xin @ Wkqv + b  -> bf16 [20000 x 1536]
        gemm_bf16<128, 0, true, true, false><<<dim3(12, mt128), blk, 0, stream>>>(
            xin, K, 0, WkqvT[l], K, 0, bkqv[l], kqvb, 1536, 0, NN, K, nullptr, nullptr);

        // k_rel (all relations): per-head batched GEMM, K=64, N=256
        gemm_bf16<128, 0, true, false, false><<<dim3(2, mt128, NH), blk, 0, stream>>>(
            kqvb, 1536, 64, WkT[l], 64, (size_t)256 * 64, nullptr,
            krelH, 256, SZH, NN, 64, nullptr, nullptr);

        for (int r = 0; r < RR; ++r)
            alpha_kernel<<<EE / 4, blk, 0, stream>>>(krelH, kqvb, ei, prel[l], r, alpha);

        softmax_stats<<<(NN * 64) / 256, blk, 0, stream>>>(alpha, rowptr, erec, lse);

        for (int r = 0; r < RR; ++r)
            wsum_kernel<<<(NN * 64) / 256, blk, 0, stream>>>(
                kqvb, alpha, lse, rowptr, erec, ei, r, wsumH);

        // agg = gelu( sum_r wsum_r @ Wv_r ) : per-head batched GEMM, K=256, N=64
        gemm_bf16<64, 2, true, false, false><<<dim3(1, mt128, NH), blk, 0, stream>>>(
            wsumH, 256, SZH, WvT[l], 256, (size_t)64 * 256, nullptr,
            aggb, 512, 64, NN, 256, nullptr, nullptr);

        // out = agg @ Wout + bout (+ skip mix on layer 1)
        if (l == 0)
            gemm_bf16<128, 0, true, true, false><<<dim3(4, mt128), blk, 0, stream>>>(
                aggb, 512, 0, WoutT[0], 512, 0, bout[0], h0b, 512, 0, NN, 512, nullptr, nullptr);
        else
            gemm_bf16<128, 0, true, true, true><<<dim3(4, mt128), blk, 0, stream>>>(
                aggb, 512, 0, WoutT[1], 512, 0, bout[1], h1b, 512, 0, NN, 512, h0b, skip1);
    }

    // node_embeds = h1 @ Wfc + bfc (f32 out)
    gemm_bf16<128, 0, false, true, false><<<dim3(2, mt128), blk, 0, stream>>>(
        h1b, 512, 0, WfcT, 512, 0, bfc, outf, 256, 0, NN, 512, nullptr, nullptr);

    // edge_embeds in 4 chunks of 40000 rows
    for (int c = 0; c < 4; ++c) {
        const float* ec = ea + (size_t)c * EE * CEDGE;
        f2b_vec<<<(EE * CEDGE / 8 + 255) / 256, blk, 0, stream>>>(ec, eab, EE * CEDGE / 8);
        gemm_bf16<128, 1, true, true, false><<<dim3(4, mt128e), blk, 0, stream>>>(
            eab, 128, 0, We1T, 128, 0, be1, eintb, 512, 0, EE, 128, nullptr, nullptr);
        gemm_bf16<128, 0, false, true, false><<<dim3(2, mt128e), blk, 0, stream>>>(
            eintb, 512, 0, We2T, 512, 0, be2,
            outf + 5120000 + (size_t)c * EE * OUTW, 256, 0, EE, 512, nullptr, nullptr);
    }
}

// Round 4
// 904.713 us; speedup vs baseline: 7.6375x; 1.1528x over previous
//
#include <hip/hip_runtime.h>
#include <cstdint>
#include <cstddef>

#define NN      20000
#define RR      4
#define EE      40000
#define CIN     256
#define CEDGE   128
#define HIDW    512
#define OUTW    256
#define NH      8
#define MEDGE   (RR*EE)
#define SCALEF  0.125f

typedef unsigned short u16;
typedef short s8v  __attribute__((ext_vector_type(8)));
typedef float f32x4 __attribute__((ext_vector_type(4)));

// ---- ws layout (BYTE offsets) ----
#define B_KQV   10240000ull             // 20000*1536*2 = 61,440,000
#define B_KREL  71680000ull             // 20000*2048*2 = 81,920,000 (wsumH overlays after alpha)
#define B_AGG   153600000ull            // 20000*512*2
#define B_H0    174080000ull            // 20000*512*2
#define B_H1    194560000ull            // 20000*512*2
#define B_ALPHA 215040000ull            // 160000*8*4 = 5,120,000 (f32)
#define B_LSE   220160000ull            // 20000*8*4 (f32); fillcnt overlay during CSR build
#define B_ROWP  220800000ull            // 20001*4 -> pad
#define B_EREC  220880128ull            // 160000*4
#define B_WTS   221520128ull            // bf16 weights, ~5.2 MB
// edge-phase overlay (node buffers below h1 are dead):
#define B_EINT  0ull                    // 160000*512*2 = 163,840,000
#define WS_NEED 227000000ull

#define SZH ((size_t)NN * 256)          // elements per head-matrix (wsumH)

__device__ __forceinline__ u16 f2b(float f) {
    unsigned u = __float_as_uint(f);
    unsigned r = (u + 0x7FFFu + ((u >> 16) & 1u)) >> 16;
    return (u16)r;
}
__device__ __forceinline__ float b2f(u16 h) { return __uint_as_float(((unsigned)h) << 16); }
__device__ __forceinline__ float gelu_exact(float x) {
    return 0.5f * x * (1.0f + erff(x * 0.70710678118654752f));
}

// =============== generic bf16 MFMA GEMM ===============
// A: M x K row-major (lda) — bf16, or f32 converted during staging when AF32.
// BT: N x K bf16 row-major (ldb). C: M x N (ldc). batched over blockIdx.z via strides.
// K%64==0, N%BN==0, M guarded (rows clamped on load).
// ACT: 0 none, 1 relu, 2 gelu. SKIP: out = g*out+(1-g)*skipx (bf16).
template<int BN, int ACT, bool OUTBF16, bool BIAS, bool SKIP, bool AF32 = false>
__global__ __launch_bounds__(256) void gemm_bf16(
    const void* __restrict__ Av, int lda, size_t astride,
    const u16* __restrict__ BT, int ldb, size_t bstride,
    const float* __restrict__ bias,
    void* __restrict__ Cv, int ldc, size_t cstride,
    int M, int K,
    const u16* __restrict__ skipx, const float* __restrict__ gatep)
{
    constexpr int FN  = BN / 32;        // frags per wave along N (wave covers BN/2)
    constexpr int NBI = BN / 32;        // B staging chunks per thread
    __shared__ __align__(16) u16 As[128 * 72];
    __shared__ __align__(16) u16 Bs[BN * 72];

    const int t = threadIdx.x, lane = t & 63, wid = t >> 6;
    const int m0 = blockIdx.y * 128, n0 = blockIdx.x * BN;
    const int z  = blockIdx.z;
    BT += (size_t)z * bstride;
    const int wm = wid >> 1, wn = wid & 1;

    f32x4 acc[4][FN];
    #pragma unroll
    for (int i = 0; i < 4; ++i)
        #pragma unroll
        for (int j = 0; j < FN; ++j)
            acc[i][j] = (f32x4){0.f, 0.f, 0.f, 0.f};

    for (int k0 = 0; k0 < K; k0 += 64) {
        #pragma unroll
        for (int i = 0; i < 4; ++i) {               // A: 128 rows x 8 chunks of 8
            int c = i * 256 + t;
            int row = c >> 3, cc = c & 7;
            int gr = m0 + row; gr = gr < M ? gr : M - 1;
            s8v v;
            if (AF32) {
                const float* Ap = (const float*)Av + (size_t)z * astride
                                + (size_t)gr * lda + k0 + cc * 8;
                float4 p = *(const float4*)Ap;
                float4 q = *(const float4*)(Ap + 4);
                v[0] = (short)f2b(p.x); v[1] = (short)f2b(p.y);
                v[2] = (short)f2b(p.z); v[3] = (short)f2b(p.w);
                v[4] = (short)f2b(q.x); v[5] = (short)f2b(q.y);
                v[6] = (short)f2b(q.z); v[7] = (short)f2b(q.w);
            } else {
                const u16* Ap = (const u16*)Av + (size_t)z * astride
                              + (size_t)gr * lda + k0 + cc * 8;
                v = *(const s8v*)Ap;
            }
            *(s8v*)&As[row * 72 + cc * 8] = v;
        }
        #pragma unroll
        for (int i = 0; i < NBI; ++i) {             // B: BN rows x 8 chunks of 8
            int c = i * 256 + t;
            int col = c >> 3, cc = c & 7;
            s8v v = *(const s8v*)(BT + (size_t)(n0 + col) * ldb + k0 + cc * 8);
            *(s8v*)&Bs[col * 72 + cc * 8] = v;
        }
        __syncthreads();
        #pragma unroll
        for (int ks = 0; ks < 2; ++ks) {
            s8v af[4], bf[FN];
            #pragma unroll
            for (int i = 0; i < 4; ++i)
                af[i] = *(const s8v*)&As[(wm * 64 + i * 16 + (lane & 15)) * 72 + ks * 32 + (lane >> 4) * 8];
            #pragma unroll
            for (int j = 0; j < FN; ++j)
                bf[j] = *(const s8v*)&Bs[(wn * (BN / 2) + j * 16 + (lane & 15)) * 72 + ks * 32 + (lane >> 4) * 8];
            #pragma unroll
            for (int i = 0; i < 4; ++i)
                #pragma unroll
                for (int j = 0; j < FN; ++j)
                    acc[i][j] = __builtin_amdgcn_mfma_f32_16x16x32_bf16(af[i], bf[j], acc[i][j], 0, 0, 0);
        }
        __syncthreads();
    }

    float gate = 1.f, ogate = 0.f;
    if (SKIP) { float s = *gatep; gate = 1.f / (1.f + expf(-s)); ogate = 1.f - gate; }
    u16*   Cb = (u16*)Cv   + (size_t)z * cstride;
    float* Cf = (float*)Cv + (size_t)z * cstride;
    #pragma unroll
    for (int i = 0; i < 4; ++i) {
        int rbase = m0 + wm * 64 + i * 16 + (lane >> 4) * 4;
        #pragma unroll
        for (int j = 0; j < FN; ++j) {
            int col = n0 + wn * (BN / 2) + j * 16 + (lane & 15);
            float bv = BIAS ? bias[col] : 0.f;
            #pragma unroll
            for (int q = 0; q < 4; ++q) {
                int r = rbase + q;
                if (r >= M) continue;
                float v = acc[i][j][q] + bv;
                if (ACT == 1) v = fmaxf(v, 0.f);
                if (ACT == 2) v = gelu_exact(v);
                if (SKIP) v = gate * v + ogate * b2f(skipx[(size_t)r * ldc + col]);
                if (OUTBF16) Cb[(size_t)r * ldc + col] = f2b(v);
                else         Cf[(size_t)r * ldc + col] = v;
            }
        }
    }
}

// =============== weight conversions ===============
// W [K x N] f32 -> WT [N x K] bf16
__global__ __launch_bounds__(256) void transpose_f2b(
    const float* __restrict__ W, u16* __restrict__ WT, int K, int N)
{
    __shared__ float tile[32][33];
    int kb = blockIdx.x * 32, nb = blockIdx.y * 32;
    int tx = threadIdx.x & 31, ty = threadIdx.x >> 5;   // ty 0..7
    #pragma unroll
    for (int i = 0; i < 32; i += 8)
        tile[ty + i][tx] = W[(size_t)(kb + ty + i) * N + nb + tx];
    __syncthreads();
    #pragma unroll
    for (int i = 0; i < 32; i += 8)
        WT[(size_t)(nb + ty + i) * K + kb + tx] = f2b(tile[tx][ty + i]);
}

// Wk[r][h][d][e] -> WkT[h][r*64+e][d]
__global__ void conv_wk(const float* __restrict__ Wk, u16* __restrict__ WkT)
{
    int idx = blockIdx.x * 256 + threadIdx.x;
    if (idx >= 8 * 256 * 64) return;
    int d = idx & 63, re = (idx >> 6) & 255, h = idx >> 14;
    int e = re & 63, r = re >> 6;
    WkT[idx] = f2b(Wk[(size_t)(((r * 8 + h) * 64 + d) * 64) + e]);
}

// Wv[r][h][d][e] -> WvT[h][e][r*64+d]
__global__ void conv_wv(const float* __restrict__ Wv, u16* __restrict__ WvT)
{
    int idx = blockIdx.x * 256 + threadIdx.x;
    if (idx >= 8 * 64 * 256) return;
    int d = idx & 63, r = (idx >> 6) & 3, e = (idx >> 8) & 63, h = idx >> 14;
    WvT[idx] = f2b(Wv[(size_t)(((r * 8 + h) * 64 + d) * 64) + e]);
}

// =============== CSR build ===============
__global__ void deg_kernel(const int* __restrict__ ei, int* __restrict__ rowptr)
{
    int idx = blockIdx.x * 256 + threadIdx.x;
    if (idx >= MEDGE) return;
    int r = idx / EE;
    atomicAdd(&rowptr[ei[idx + (r + 1) * EE]], 1);
}

__global__ __launch_bounds__(256) void scan_kernel(int* __restrict__ rowptr)
{
    __shared__ int buf[256];
    __shared__ int carry;
    const int t = threadIdx.x;
    if (t == 0) carry = 0;
    __syncthreads();
    for (int base = 0; base < NN; base += 256) {
        int i = base + t;
        int v = (i < NN) ? rowptr[i] : 0;
        buf[t] = v;
        __syncthreads();
        for (int off = 1; off < 256; off <<= 1) {
            int tv = (t >= off) ? buf[t - off] : 0;
            __syncthreads();
            buf[t] += tv;
            __syncthreads();
        }
        int total = buf[255];
        int excl = buf[t] - v;
        int c = carry;
        __syncthreads();
        if (i < NN) rowptr[i] = c + excl;
        if (t == 0) carry = c + total;
        __syncthreads();
    }
    if (t == 0) rowptr[NN] = carry;
}

__global__ void fill_kernel(const int* __restrict__ ei, const int* __restrict__ rowptr,
                            int* __restrict__ fillcnt, int* __restrict__ erec)
{
    int idx = blockIdx.x * 256 + threadIdx.x;
    if (idx >= MEDGE) return;
    int r = idx / EE;
    int dst = ei[idx + (r + 1) * EE];
    int pos = rowptr[dst] + atomicAdd(&fillcnt[dst], 1);
    erec[pos] = idx;
}

// =============== fused alpha + online-LSE (all relations; wave per node) ===============
// krel2 layout: [n][h*256 + r*64 + d] bf16 (one 2KB row per src node)
__global__ __launch_bounds__(256) void alpha_stats(
    const u16* __restrict__ krel2, const u16* __restrict__ kqvb,
    const int* __restrict__ ei, const int* __restrict__ rowptr,
    const int* __restrict__ erec, const float* __restrict__ prel,
    float* __restrict__ alpha, float* __restrict__ lse)
{
    int n    = (blockIdx.x * 256 + threadIdx.x) >> 6;
    int lane = threadIdx.x & 63;
    if (n >= NN) return;
    int p0 = rowptr[n], p1 = rowptr[n + 1];
    int h = lane >> 3, sub = lane & 7;
    s8v qv = *(const s8v*)(kqvb + (size_t)n * 1536 + 512 + h * 64 + sub * 8);
    float qf[8];
    #pragma unroll
    for (int q = 0; q < 8; ++q) qf[q] = b2f((u16)qv[q]);
    float m = -3.0e38f, ssum = 0.f;
    for (int j = p0; j < p1; ++j) {
        int idx = erec[j];
        int r = idx / EE;
        int src = ei[idx + r * EE];
        s8v kv = *(const s8v*)(krel2 + (size_t)src * 2048 + h * 256 + r * 64 + sub * 8);
        float s = 0.f;
        #pragma unroll
        for (int q = 0; q < 8; ++q) s += b2f((u16)kv[q]) * qf[q];
        s += __shfl_xor(s, 1);
        s += __shfl_xor(s, 2);
        s += __shfl_xor(s, 4);
        float a = s * prel[r * NH + h] * SCALEF;
        if (sub == 0) alpha[(size_t)idx * 8 + h] = a;
        float mn = fmaxf(m, a);
        ssum = ssum * expf(m - mn) + expf(a - mn);
        m = mn;
    }
    if (sub == 0) lse[(size_t)n * 8 + h] = m + logf(ssum + 1e-16f);
}

// =============== weighted v aggregation (all relations; wave per node; one CSR scan) ===============
// writes wsumH[h][n][r*64 + d] bf16
__global__ __launch_bounds__(256) void wsum_all(
    const u16* __restrict__ kqvb, const float* __restrict__ alpha,
    const float* __restrict__ lse, const int* __restrict__ rowptr,
    const int* __restrict__ erec, const int* __restrict__ ei,
    u16* __restrict__ wsumH)
{
    int n    = (blockIdx.x * 256 + threadIdx.x) >> 6;
    int lane = threadIdx.x & 63;
    if (n >= NN) return;
    int p0 = rowptr[n], p1 = rowptr[n + 1];
    int h = lane >> 3;
    float ls = lse[(size_t)n * 8 + h];
    float a0[8] = {}, a1[8] = {}, a2[8] = {}, a3[8] = {};
    for (int j = p0; j < p1; ++j) {
        int idx = erec[j];
        int r = idx / EE;                 // wave-uniform
        int src = ei[idx + r * EE];
        float w = expf(alpha[(size_t)idx * 8 + h] - ls);
        s8v vv = *(const s8v*)(kqvb + (size_t)src * 1536 + 1024 + lane * 8);
        if (r == 0) {
            #pragma unroll
            for (int q = 0; q < 8; ++q) a0[q] += w * b2f((u16)vv[q]);
        } else if (r == 1) {
            #pragma unroll
            for (int q = 0; q < 8; ++q) a1[q] += w * b2f((u16)vv[q]);
        } else if (r == 2) {
            #pragma unroll
            for (int q = 0; q < 8; ++q) a2[q] += w * b2f((u16)vv[q]);
        } else {
            #pragma unroll
            for (int q = 0; q < 8; ++q) a3[q] += w * b2f((u16)vv[q]);
        }
    }
    u16* base = wsumH + (size_t)h * SZH + (size_t)n * 256 + (lane & 7) * 8;
    s8v o;
    #pragma unroll
    for (int q = 0; q < 8; ++q) o[q] = (short)f2b(a0[q]);
    *(s8v*)(base + 0)   = o;
    #pragma unroll
    for (int q = 0; q < 8; ++q) o[q] = (short)f2b(a1[q]);
    *(s8v*)(base + 64)  = o;
    #pragma unroll
    for (int q = 0; q < 8; ++q) o[q] = (short)f2b(a2[q]);
    *(s8v*)(base + 128) = o;
    #pragma unroll
    for (int q = 0; q < 8; ++q) o[q] = (short)f2b(a3[q]);
    *(s8v*)(base + 192) = o;
}

extern "C" void kernel_launch(void* const* d_in, const int* in_sizes, int n_in,
                              void* d_out, int out_size, void* d_ws, size_t ws_size,
                              hipStream_t stream)
{
    const float* x    = (const float*)d_in[0];
    const int*   ei   = (const int*)d_in[1];
    const float* ea   = (const float*)d_in[2];
    const float* Wkqv[2] = {(const float*)d_in[3],  (const float*)d_in[10]};
    const float* bkqv[2] = {(const float*)d_in[4],  (const float*)d_in[11]};
    const float* Wk[2]   = {(const float*)d_in[5],  (const float*)d_in[12]};
    const float* Wv[2]   = {(const float*)d_in[6],  (const float*)d_in[13]};
    const float* prel[2] = {(const float*)d_in[7],  (const float*)d_in[14]};
    const float* Wout[2] = {(const float*)d_in[8],  (const float*)d_in[15]};
    const float* bout[2] = {(const float*)d_in[9],  (const float*)d_in[16]};
    const float* skip1 = (const float*)d_in[17];
    const float* Wfc   = (const float*)d_in[18];
    const float* bfc   = (const float*)d_in[19];
    const float* We1   = (const float*)d_in[20];
    const float* be1   = (const float*)d_in[21];
    const float* We2   = (const float*)d_in[22];
    const float* be2   = (const float*)d_in[23];

    if (ws_size < WS_NEED) return;

    char* wsb = (char*)d_ws;
    u16*   kqvb  = (u16*)(wsb + B_KQV);
    u16*   krel2 = (u16*)(wsb + B_KREL);
    u16*   wsumH = krel2;                    // overlay (krel dead after alpha_stats)
    u16*   aggb  = (u16*)(wsb + B_AGG);
    u16*   h0b   = (u16*)(wsb + B_H0);
    u16*   h1b   = (u16*)(wsb + B_H1);
    float* alpha = (float*)(wsb + B_ALPHA);
    float* lse   = (float*)(wsb + B_LSE);
    int*   fillcnt = (int*)(wsb + B_LSE);    // build-time overlay
    int*   rowptr  = (int*)(wsb + B_ROWP);
    int*   erec    = (int*)(wsb + B_EREC);
    u16*   eintb = (u16*)(wsb + B_EINT);     // edge-phase overlay
    float* outf  = (float*)d_out;

    // bf16 weight arena
    u16* wt = (u16*)(wsb + B_WTS);
    u16* WkqvT[2] = {wt, wt + 393216};              wt += 393216 + 786432;
    u16* WkT[2]   = {wt, wt + 131072};              wt += 262144;
    u16* WvT[2]   = {wt, wt + 131072};              wt += 262144;
    u16* WoutT[2] = {wt, wt + 262144};              wt += 524288;
    u16* WfcT     = wt;                             wt += 131072;
    u16* We1T     = wt;                             wt += 65536;
    u16* We2T     = wt;

    const dim3 blk(256);
    const int mt128  = (NN + 127) / 128;   // 157
    const int mtE    = MEDGE / 128;        // 1250

    // ---- weight conversions ----
    transpose_f2b<<<dim3(CIN / 32, 1536 / 32), blk, 0, stream>>>(Wkqv[0], WkqvT[0], CIN, 1536);
    transpose_f2b<<<dim3(HIDW / 32, 1536 / 32), blk, 0, stream>>>(Wkqv[1], WkqvT[1], HIDW, 1536);
    transpose_f2b<<<dim3(HIDW / 32, HIDW / 32), blk, 0, stream>>>(Wout[0], WoutT[0], HIDW, HIDW);
    transpose_f2b<<<dim3(HIDW / 32, HIDW / 32), blk, 0, stream>>>(Wout[1], WoutT[1], HIDW, HIDW);
    transpose_f2b<<<dim3(HIDW / 32, OUTW / 32), blk, 0, stream>>>(Wfc, WfcT, HIDW, OUTW);
    transpose_f2b<<<dim3(CEDGE / 32, HIDW / 32), blk, 0, stream>>>(We1, We1T, CEDGE, HIDW);
    transpose_f2b<<<dim3(HIDW / 32, OUTW / 32), blk, 0, stream>>>(We2, We2T, HIDW, OUTW);
    for (int l = 0; l < 2; ++l) {
        conv_wk<<<(131072 + 255) / 256, blk, 0, stream>>>(Wk[l], WkT[l]);
        conv_wv<<<(131072 + 255) / 256, blk, 0, stream>>>(Wv[l], WvT[l]);
    }

    // ---- CSR build ----
    hipMemsetAsync(rowptr, 0, (NN + 1) * sizeof(int), stream);
    hipMemsetAsync(fillcnt, 0, NN * sizeof(int), stream);
    deg_kernel<<<(MEDGE + 255) / 256, blk, 0, stream>>>(ei, rowptr);
    scan_kernel<<<1, blk, 0, stream>>>(rowptr);
    fill_kernel<<<(MEDGE + 255) / 256, blk, 0, stream>>>(ei, rowptr, fillcnt, erec);

    for (int l = 0; l < 2; ++l) {
        int K = (l == 0) ? CIN : HIDW;

        // kqv = xin @ Wkqv + b  -> bf16 [20000 x 1536]   (layer 0 reads f32 x directly)
        if (l == 0)
            gemm_bf16<128, 0, true, true, false, true><<<dim3(12, mt128), blk, 0, stream>>>(
                (const void*)x, K, 0, WkqvT[0], K, 0, bkqv[0], kqvb, 1536, 0, NN, K, nullptr, nullptr);
        else
            gemm_bf16<128, 0, true, true, false><<<dim3(12, mt128), blk, 0, stream>>>(
                (const void*)h0b, K, 0, WkqvT[1], K, 0, bkqv[1], kqvb, 1536, 0, NN, K, nullptr, nullptr);

        // k_rel (all relations): per-head batched GEMM, K=64, N=256; out [n][h*256+r*64+e]
        gemm_bf16<128, 0, true, false, false><<<dim3(2, mt128, NH), blk, 0, stream>>>(
            (const void*)kqvb, 1536, 64, WkT[l], 64, (size_t)256 * 64, nullptr,
            krel2, 2048, 256, NN, 64, nullptr, nullptr);

        alpha_stats<<<(NN * 64) / 256, blk, 0, stream>>>(
            krel2, kqvb, ei, rowptr, erec, prel[l], alpha, lse);

        wsum_all<<<(NN * 64) / 256, blk, 0, stream>>>(
            kqvb, alpha, lse, rowptr, erec, ei, wsumH);

        // agg = gelu( sum_r wsum_r @ Wv_r ) : per-head batched GEMM, K=256, N=64
        gemm_bf16<64, 2, true, false, false><<<dim3(1, mt128, NH), blk, 0, stream>>>(
            (const void*)wsumH, 256, SZH, WvT[l], 256, (size_t)64 * 256, nullptr,
            aggb, 512, 64, NN, 256, nullptr, nullptr);

        // out = agg @ Wout + bout (+ skip mix on layer 1)
        if (l == 0)
            gemm_bf16<128, 0, true, true, false><<<dim3(4, mt128), blk, 0, stream>>>(
                (const void*)aggb, 512, 0, WoutT[0], 512, 0, bout[0], h0b, 512, 0, NN, 512, nullptr, nullptr);
        else
            gemm_bf16<128, 0, true, true, true><<<dim3(4, mt128), blk, 0, stream>>>(
                (const void*)aggb, 512, 0, WoutT[1], 512, 0, bout[1], h1b, 512, 0, NN, 512, h0b, skip1);
    }

    // node_embeds = h1 @ Wfc + bfc (f32 out)
    gemm_bf16<128, 0, false, true, false><<<dim3(2, mt128), blk, 0, stream>>>(
        (const void*)h1b, 512, 0, WfcT, 512, 0, bfc, outf, 256, 0, NN, 512, nullptr, nullptr);

    // edge_embeds = relu(ea @ We1 + be1) @ We2 + be2, full 160000 rows (f32 A read directly)
    gemm_bf16<128, 1, true, true, false, true><<<dim3(4, mtE), blk, 0, stream>>>(
        (const void*)ea, 128, 0, We1T, 128, 0, be1, eintb, 512, 0, MEDGE, 128, nullptr, nullptr);
    gemm_bf16<128, 0, false, true, false><<<dim3(2, mtE), blk, 0, stream>>>(
        (const void*)eintb, 512, 0, We2T, 512, 0, be2,
        outf + 5120000, 256, 0, MEDGE, 512, nullptr, nullptr);
}

// Round 5
// 844.147 us; speedup vs baseline: 8.1855x; 1.0717x over previous
//
#include <hip/hip_runtime.h>
#include <cstdint>
#include <cstddef>

#define NN      20000
#define RR      4
#define EE      40000
#define CIN     256
#define CEDGE   128
#define HIDW    512
#define OUTW    256
#define NH      8
#define MEDGE   (RR*EE)
#define SCALEF  0.125f

typedef unsigned short u16;
typedef short s8v  __attribute__((ext_vector_type(8)));
typedef float f32x4 __attribute__((ext_vector_type(4)));

// ---- ws layout (BYTE offsets) ----
#define B_KQV   10240000ull             // 20000*1536*2 = 61,440,000
#define B_KREL  71680000ull             // 20000*2048*2 = 81,920,000 (wsumH overlays after alpha)
#define B_AGG   153600000ull            // 20000*512*2
#define B_H0    174080000ull            // 20000*512*2
#define B_H1    194560000ull            // 20000*512*2
#define B_ALPHA 215040000ull            // 160000*8*4 = 5,120,000 (f32)
#define B_LSE   220160000ull            // 20000*8*4 (f32); fillcnt overlay during CSR build
#define B_ROWP  220800000ull            // 20001*4 -> pad
#define B_EREC  220880128ull            // 160000*4
#define B_WTS   221520128ull            // bf16 weights, ~5.2 MB
// edge-phase overlay (node buffers below h1 are dead):
#define B_EINT  0ull                    // 160000*512*2 = 163,840,000
#define WS_NEED 227000000ull

#define SZH ((size_t)NN * 256)          // elements per head-matrix (wsumH)

__device__ __forceinline__ u16 f2b(float f) {
    unsigned u = __float_as_uint(f);
    unsigned r = (u + 0x7FFFu + ((u >> 16) & 1u)) >> 16;
    return (u16)r;
}
__device__ __forceinline__ float b2f(u16 h) { return __uint_as_float(((unsigned)h) << 16); }
__device__ __forceinline__ float gelu_exact(float x) {
    return 0.5f * x * (1.0f + erff(x * 0.70710678118654752f));
}

// async global->LDS, 16 bytes per lane; LDS dest must be wave-uniform base
__device__ __forceinline__ void gl_lds16(const u16* g, u16* l) {
    __builtin_amdgcn_global_load_lds(
        (const __attribute__((address_space(1))) void*)g,
        (__attribute__((address_space(3))) void*)l, 16, 0, 0);
}

// =============== generic bf16 MFMA GEMM (global_load_lds + XOR-swizzled LDS) ===============
// A: M x K row-major (lda) — bf16, or f32 converted during staging when AF32.
// BT: N x K bf16 row-major (ldb). C: M x N (ldc). batched over blockIdx.z via strides.
// K%64==0, N%BN==0, M guarded (rows clamped on load).
// LDS layout: As[row][chunk] (chunk = 8 elems / 16B) holds global chunk (chunk ^ (row&7)).
// ACT: 0 none, 1 relu, 2 gelu. SKIP: out = g*out+(1-g)*skipx (bf16).
template<int BN, int ACT, bool OUTBF16, bool BIAS, bool SKIP, bool AF32 = false>
__global__ __launch_bounds__(256) void gemm_bf16(
    const void* __restrict__ Av, int lda, size_t astride,
    const u16* __restrict__ BT, int ldb, size_t bstride,
    const float* __restrict__ bias,
    void* __restrict__ Cv, int ldc, size_t cstride,
    int M, int K,
    const u16* __restrict__ skipx, const float* __restrict__ gatep)
{
    constexpr int FN = BN / 32;         // frags per wave along N (wave covers BN/2)
    constexpr int BI = BN / 32;         // B stage instructions per wave
    __shared__ __align__(16) u16 As[128 * 64];
    __shared__ __align__(16) u16 Bs[BN * 64];

    const int t = threadIdx.x, lane = t & 63, wid = t >> 6;
    const int m0 = blockIdx.y * 128, n0 = blockIdx.x * BN;
    const int z  = blockIdx.z;
    const u16*   Bz = BT + (size_t)z * bstride;
    const float* Af = (const float*)Av + (AF32 ? (size_t)z * astride : 0);
    const u16*   Au = (const u16*)Av   + (AF32 ? 0 : (size_t)z * astride);
    const int wm = wid >> 1, wn = wid & 1;

    // per-lane staging constants: lane covers row-in-group (lane>>3), swizzled k-chunk
    const int srow   = lane >> 3;
    const int schunk = (lane & 7) ^ srow;

    f32x4 acc[4][FN];
    #pragma unroll
    for (int i = 0; i < 4; ++i)
        #pragma unroll
        for (int j = 0; j < FN; ++j)
            acc[i][j] = (f32x4){0.f, 0.f, 0.f, 0.f};

    for (int k0 = 0; k0 < K; k0 += 64) {
        if (AF32) {
            // reg staging with f32->bf16 convert; write to swizzled chunk
            #pragma unroll
            for (int i = 0; i < 4; ++i) {
                int c = i * 256 + t;
                int row = c >> 3, cc = c & 7;
                int gr = m0 + row; gr = gr < M ? gr : M - 1;
                const float* Ap = Af + (size_t)gr * lda + k0 + cc * 8;
                float4 p = *(const float4*)Ap;
                float4 q = *(const float4*)(Ap + 4);
                s8v v;
                v[0] = (short)f2b(p.x); v[1] = (short)f2b(p.y);
                v[2] = (short)f2b(p.z); v[3] = (short)f2b(p.w);
                v[4] = (short)f2b(q.x); v[5] = (short)f2b(q.y);
                v[6] = (short)f2b(q.z); v[7] = (short)f2b(q.w);
                *(s8v*)&As[row * 64 + ((cc ^ (row & 7)) << 3)] = v;
            }
        } else {
            // async staging: 16 wave-instructions cover 128 rows x 64 k
            #pragma unroll
            for (int i = 0; i < 4; ++i) {
                int t4 = wid * 4 + i;
                int row = t4 * 8 + srow;
                int gr = m0 + row; gr = gr < M ? gr : M - 1;
                gl_lds16(Au + (size_t)gr * lda + k0 + schunk * 8, &As[t4 * 512]);
            }
        }
        #pragma unroll
        for (int i = 0; i < BI; ++i) {
            int tb = wid * BI + i;
            int col = n0 + tb * 8 + srow;
            gl_lds16(Bz + (size_t)col * ldb + k0 + schunk * 8, &Bs[tb * 512]);
        }
        __syncthreads();   // drains vmcnt (incl. global_load_lds) + lgkmcnt
        #pragma unroll
        for (int ks = 0; ks < 2; ++ks) {
            s8v af[4], bf[FN];
            #pragma unroll
            for (int i = 0; i < 4; ++i) {
                int arow = wm * 64 + i * 16 + (lane & 15);
                int ac   = (ks * 4 + (lane >> 4)) ^ (lane & 7);
                af[i] = *(const s8v*)&As[arow * 64 + ac * 8];
            }
            #pragma unroll
            for (int j = 0; j < FN; ++j) {
                int brow = wn * (BN / 2) + j * 16 + (lane & 15);
                int bc   = (ks * 4 + (lane >> 4)) ^ (lane & 7);
                bf[j] = *(const s8v*)&Bs[brow * 64 + bc * 8];
            }
            #pragma unroll
            for (int i = 0; i < 4; ++i)
                #pragma unroll
                for (int j = 0; j < FN; ++j)
                    acc[i][j] = __builtin_amdgcn_mfma_f32_16x16x32_bf16(af[i], bf[j], acc[i][j], 0, 0, 0);
        }
        __syncthreads();
    }

    float gate = 1.f, ogate = 0.f;
    if (SKIP) { float s = *gatep; gate = 1.f / (1.f + expf(-s)); ogate = 1.f - gate; }
    u16*   Cb = (u16*)Cv   + (size_t)z * cstride;
    float* Cf = (float*)Cv + (size_t)z * cstride;
    #pragma unroll
    for (int i = 0; i < 4; ++i) {
        int rbase = m0 + wm * 64 + i * 16 + (lane >> 4) * 4;
        #pragma unroll
        for (int j = 0; j < FN; ++j) {
            int col = n0 + wn * (BN / 2) + j * 16 + (lane & 15);
            float bv = BIAS ? bias[col] : 0.f;
            #pragma unroll
            for (int q = 0; q < 4; ++q) {
                int r = rbase + q;
                if (r >= M) continue;
                float v = acc[i][j][q] + bv;
                if (ACT == 1) v = fmaxf(v, 0.f);
                if (ACT == 2) v = gelu_exact(v);
                if (SKIP) v = gate * v + ogate * b2f(skipx[(size_t)r * ldc + col]);
                if (OUTBF16) Cb[(size_t)r * ldc + col] = f2b(v);
                else         Cf[(size_t)r * ldc + col] = v;
            }
        }
    }
}

// =============== weight conversions ===============
// W [K x N] f32 -> WT [N x K] bf16
__global__ __launch_bounds__(256) void transpose_f2b(
    const float* __restrict__ W, u16* __restrict__ WT, int K, int N)
{
    __shared__ float tile[32][33];
    int kb = blockIdx.x * 32, nb = blockIdx.y * 32;
    int tx = threadIdx.x & 31, ty = threadIdx.x >> 5;   // ty 0..7
    #pragma unroll
    for (int i = 0; i < 32; i += 8)
        tile[ty + i][tx] = W[(size_t)(kb + ty + i) * N + nb + tx];
    __syncthreads();
    #pragma unroll
    for (int i = 0; i < 32; i += 8)
        WT[(size_t)(nb + ty + i) * K + kb + tx] = f2b(tile[tx][ty + i]);
}

// Wk[r][h][d][e] -> WkT[h][r*64+e][d]
__global__ void conv_wk(const float* __restrict__ Wk, u16* __restrict__ WkT)
{
    int idx = blockIdx.x * 256 + threadIdx.x;
    if (idx >= 8 * 256 * 64) return;
    int d = idx & 63, re = (idx >> 6) & 255, h = idx >> 14;
    int e = re & 63, r = re >> 6;
    WkT[idx] = f2b(Wk[(size_t)(((r * 8 + h) * 64 + d) * 64) + e]);
}

// Wv[r][h][d][e] -> WvT[h][e][r*64+d]
__global__ void conv_wv(const float* __restrict__ Wv, u16* __restrict__ WvT)
{
    int idx = blockIdx.x * 256 + threadIdx.x;
    if (idx >= 8 * 64 * 256) return;
    int d = idx & 63, r = (idx >> 6) & 3, e = (idx >> 8) & 63, h = idx >> 14;
    WvT[idx] = f2b(Wv[(size_t)(((r * 8 + h) * 64 + d) * 64) + e]);
}

// =============== CSR build ===============
__global__ void deg_kernel(const int* __restrict__ ei, int* __restrict__ rowptr)
{
    int idx = blockIdx.x * 256 + threadIdx.x;
    if (idx >= MEDGE) return;
    int r = idx / EE;
    atomicAdd(&rowptr[ei[idx + (r + 1) * EE]], 1);
}

__global__ __launch_bounds__(256) void scan_kernel(int* __restrict__ rowptr)
{
    __shared__ int buf[256];
    __shared__ int carry;
    const int t = threadIdx.x;
    if (t == 0) carry = 0;
    __syncthreads();
    for (int base = 0; base < NN; base += 256) {
        int i = base + t;
        int v = (i < NN) ? rowptr[i] : 0;
        buf[t] = v;
        __syncthreads();
        for (int off = 1; off < 256; off <<= 1) {
            int tv = (t >= off) ? buf[t - off] : 0;
            __syncthreads();
            buf[t] += tv;
            __syncthreads();
        }
        int total = buf[255];
        int excl = buf[t] - v;
        int c = carry;
        __syncthreads();
        if (i < NN) rowptr[i] = c + excl;
        if (t == 0) carry = c + total;
        __syncthreads();
    }
    if (t == 0) rowptr[NN] = carry;
}

__global__ void fill_kernel(const int* __restrict__ ei, const int* __restrict__ rowptr,
                            int* __restrict__ fillcnt, int* __restrict__ erec)
{
    int idx = blockIdx.x * 256 + threadIdx.x;
    if (idx >= MEDGE) return;
    int r = idx / EE;
    int dst = ei[idx + (r + 1) * EE];
    int pos = rowptr[dst] + atomicAdd(&fillcnt[dst], 1);
    erec[pos] = idx;
}

// =============== fused alpha + online-LSE (all relations; wave per node) ===============
// krel2 layout: [n][h*256 + r*64 + d] bf16 (one 2KB row per src node)
__global__ __launch_bounds__(256) void alpha_stats(
    const u16* __restrict__ krel2, const u16* __restrict__ kqvb,
    const int* __restrict__ ei, const int* __restrict__ rowptr,
    const int* __restrict__ erec, const float* __restrict__ prel,
    float* __restrict__ alpha, float* __restrict__ lse)
{
    int n    = (blockIdx.x * 256 + threadIdx.x) >> 6;
    int lane = threadIdx.x & 63;
    if (n >= NN) return;
    int p0 = rowptr[n], p1 = rowptr[n + 1];
    int h = lane >> 3, sub = lane & 7;
    s8v qv = *(const s8v*)(kqvb + (size_t)n * 1536 + 512 + h * 64 + sub * 8);
    float qf[8];
    #pragma unroll
    for (int q = 0; q < 8; ++q) qf[q] = b2f((u16)qv[q]);
    float m = -3.0e38f, ssum = 0.f;
    for (int j = p0; j < p1; ++j) {
        int idx = erec[j];
        int r = idx / EE;
        int src = ei[idx + r * EE];
        s8v kv = *(const s8v*)(krel2 + (size_t)src * 2048 + h * 256 + r * 64 + sub * 8);
        float s = 0.f;
        #pragma unroll
        for (int q = 0; q < 8; ++q) s += b2f((u16)kv[q]) * qf[q];
        s += __shfl_xor(s, 1);
        s += __shfl_xor(s, 2);
        s += __shfl_xor(s, 4);
        float a = s * prel[r * NH + h] * SCALEF;
        if (sub == 0) alpha[(size_t)idx * 8 + h] = a;
        float mn = fmaxf(m, a);
        ssum = ssum * expf(m - mn) + expf(a - mn);
        m = mn;
    }
    if (sub == 0) lse[(size_t)n * 8 + h] = m + logf(ssum + 1e-16f);
}

// =============== weighted v aggregation (all relations; wave per node; one CSR scan) ===============
// writes wsumH[h][n][r*64 + d] bf16
__global__ __launch_bounds__(256) void wsum_all(
    const u16* __restrict__ kqvb, const float* __restrict__ alpha,
    const float* __restrict__ lse, const int* __restrict__ rowptr,
    const int* __restrict__ erec, const int* __restrict__ ei,
    u16* __restrict__ wsumH)
{
    int n    = (blockIdx.x * 256 + threadIdx.x) >> 6;
    int lane = threadIdx.x & 63;
    if (n >= NN) return;
    int p0 = rowptr[n], p1 = rowptr[n + 1];
    int h = lane >> 3;
    float ls = lse[(size_t)n * 8 + h];
    float a0[8] = {}, a1[8] = {}, a2[8] = {}, a3[8] = {};
    for (int j = p0; j < p1; ++j) {
        int idx = erec[j];
        int r = idx / EE;                 // wave-uniform
        int src = ei[idx + r * EE];
        float w = expf(alpha[(size_t)idx * 8 + h] - ls);
        s8v vv = *(const s8v*)(kqvb + (size_t)src * 1536 + 1024 + lane * 8);
        if (r == 0) {
            #pragma unroll
            for (int q = 0; q < 8; ++q) a0[q] += w * b2f((u16)vv[q]);
        } else if (r == 1) {
            #pragma unroll
            for (int q = 0; q < 8; ++q) a1[q] += w * b2f((u16)vv[q]);
        } else if (r == 2) {
            #pragma unroll
            for (int q = 0; q < 8; ++q) a2[q] += w * b2f((u16)vv[q]);
        } else {
            #pragma unroll
            for (int q = 0; q < 8; ++q) a3[q] += w * b2f((u16)vv[q]);
        }
    }
    u16* base = wsumH + (size_t)h * SZH + (size_t)n * 256 + (lane & 7) * 8;
    s8v o;
    #pragma unroll
    for (int q = 0; q < 8; ++q) o[q] = (short)f2b(a0[q]);
    *(s8v*)(base + 0)   = o;
    #pragma unroll
    for (int q = 0; q < 8; ++q) o[q] = (short)f2b(a1[q]);
    *(s8v*)(base + 64)  = o;
    #pragma unroll
    for (int q = 0; q < 8; ++q) o[q] = (short)f2b(a2[q]);
    *(s8v*)(base + 128) = o;
    #pragma unroll
    for (int q = 0; q < 8; ++q) o[q] = (short)f2b(a3[q]);
    *(s8v*)(base + 192) = o;
}

extern "C" void kernel_launch(void* const* d_in, const int* in_sizes, int n_in,
                              void* d_out, int out_size, void* d_ws, size_t ws_size,
                              hipStream_t stream)
{
    const float* x    = (const float*)d_in[0];
    const int*   ei   = (const int*)d_in[1];
    const float* ea   = (const float*)d_in[2];
    const float* Wkqv[2] = {(const float*)d_in[3],  (const float*)d_in[10]};
    const float* bkqv[2] = {(const float*)d_in[4],  (const float*)d_in[11]};
    const float* Wk[2]   = {(const float*)d_in[5],  (const float*)d_in[12]};
    const float* Wv[2]   = {(const float*)d_in[6],  (const float*)d_in[13]};
    const float* prel[2] = {(const float*)d_in[7],  (const float*)d_in[14]};
    const float* Wout[2] = {(const float*)d_in[8],  (const float*)d_in[15]};
    const float* bout[2] = {(const float*)d_in[9],  (const float*)d_in[16]};
    const float* skip1 = (const float*)d_in[17];
    const float* Wfc   = (const float*)d_in[18];
    const float* bfc   = (const float*)d_in[19];
    const float* We1   = (const float*)d_in[20];
    const float* be1   = (const float*)d_in[21];
    const float* We2   = (const float*)d_in[22];
    const float* be2   = (const float*)d_in[23];

    if (ws_size < WS_NEED) return;

    char* wsb = (char*)d_ws;
    u16*   kqvb  = (u16*)(wsb + B_KQV);
    u16*   krel2 = (u16*)(wsb + B_KREL);
    u16*   wsumH = krel2;                    // overlay (krel dead after alpha_stats)
    u16*   aggb  = (u16*)(wsb + B_AGG);
    u16*   h0b   = (u16*)(wsb + B_H0);
    u16*   h1b   = (u16*)(wsb + B_H1);
    float* alpha = (float*)(wsb + B_ALPHA);
    float* lse   = (float*)(wsb + B_LSE);
    int*   fillcnt = (int*)(wsb + B_LSE);    // build-time overlay
    int*   rowptr  = (int*)(wsb + B_ROWP);
    int*   erec    = (int*)(wsb + B_EREC);
    u16*   eintb = (u16*)(wsb + B_EINT);     // edge-phase overlay
    float* outf  = (float*)d_out;

    // bf16 weight arena
    u16* wt = (u16*)(wsb + B_WTS);
    u16* WkqvT[2] = {wt, wt + 393216};              wt += 393216 + 786432;
    u16* WkT[2]   = {wt, wt + 131072};              wt += 262144;
    u16* WvT[2]   = {wt, wt + 131072};              wt += 262144;
    u16* WoutT[2] = {wt, wt + 262144};              wt += 524288;
    u16* WfcT     = wt;                             wt += 131072;
    u16* We1T     = wt;                             wt += 65536;
    u16* We2T     = wt;

    const dim3 blk(256);
    const int mt128  = (NN + 127) / 128;   // 157
    const int mtE    = MEDGE / 128;        // 1250

    // ---- weight conversions ----
    transpose_f2b<<<dim3(CIN / 32, 1536 / 32), blk, 0, stream>>>(Wkqv[0], WkqvT[0], CIN, 1536);
    transpose_f2b<<<dim3(HIDW / 32, 1536 / 32), blk, 0, stream>>>(Wkqv[1], WkqvT[1], HIDW, 1536);
    transpose_f2b<<<dim3(HIDW / 32, HIDW / 32), blk, 0, stream>>>(Wout[0], WoutT[0], HIDW, HIDW);
    transpose_f2b<<<dim3(HIDW / 32, HIDW / 32), blk, 0, stream>>>(Wout[1], WoutT[1], HIDW, HIDW);
    transpose_f2b<<<dim3(HIDW / 32, OUTW / 32), blk, 0, stream>>>(Wfc, WfcT, HIDW, OUTW);
    transpose_f2b<<<dim3(CEDGE / 32, HIDW / 32), blk, 0, stream>>>(We1, We1T, CEDGE, HIDW);
    transpose_f2b<<<dim3(HIDW / 32, OUTW / 32), blk, 0, stream>>>(We2, We2T, HIDW, OUTW);
    for (int l = 0; l < 2; ++l) {
        conv_wk<<<(131072 + 255) / 256, blk, 0, stream>>>(Wk[l], WkT[l]);
        conv_wv<<<(131072 + 255) / 256, blk, 0, stream>>>(Wv[l], WvT[l]);
    }

    // ---- CSR build ----
    hipMemsetAsync(rowptr, 0, (NN + 1) * sizeof(int), stream);
    hipMemsetAsync(fillcnt, 0, NN * sizeof(int), stream);
    deg_kernel<<<(MEDGE + 255) / 256, blk, 0, stream>>>(ei, rowptr);
    scan_kernel<<<1, blk, 0, stream>>>(rowptr);
    fill_kernel<<<(MEDGE + 255) / 256, blk, 0, stream>>>(ei, rowptr, fillcnt, erec);

    for (int l = 0; l < 2; ++l) {
        int K = (l == 0) ? CIN : HIDW;

        // kqv = xin @ Wkqv + b  -> bf16 [20000 x 1536]   (layer 0 reads f32 x directly)
        if (l == 0)
            gemm_bf16<128, 0, true, true, false, true><<<dim3(12, mt128), blk, 0, stream>>>(
                (const void*)x, K, 0, WkqvT[0], K, 0, bkqv[0], kqvb, 1536, 0, NN, K, nullptr, nullptr);
        else
            gemm_bf16<128, 0, true, true, false><<<dim3(12, mt128), blk, 0, stream>>>(
                (const void*)h0b, K, 0, WkqvT[1], K, 0, bkqv[1], kqvb, 1536, 0, NN, K, nullptr, nullptr);

        // k_rel (all relations): per-head batched GEMM, K=64, N=256; out [n][h*256+r*64+e]
        gemm_bf16<128, 0, true, false, false><<<dim3(2, mt128, NH), blk, 0, stream>>>(
            (const void*)kqvb, 1536, 64, WkT[l], 64, (size_t)256 * 64, nullptr,
            krel2, 2048, 256, NN, 64, nullptr, nullptr);

        alpha_stats<<<(NN * 64) / 256, blk, 0, stream>>>(
            krel2, kqvb, ei, rowptr, erec, prel[l], alpha, lse);

        wsum_all<<<(NN * 64) / 256, blk, 0, stream>>>(
            kqvb, alpha, lse, rowptr, erec, ei, wsumH);

        // agg = gelu( sum_r wsum_r @ Wv_r ) : per-head batched GEMM, K=256, N=64
        gemm_bf16<64, 2, true, false, false><<<dim3(1, mt128, NH), blk, 0, stream>>>(
            (const void*)wsumH, 256, SZH, WvT[l], 256, (size_t)64 * 256, nullptr,
            aggb, 512, 64, NN, 256, nullptr, nullptr);

        // out = agg @ Wout + bout (+ skip mix on layer 1)
        if (l == 0)
            gemm_bf16<128, 0, true, true, false><<<dim3(4, mt128), blk, 0, stream>>>(
                (const void*)aggb, 512, 0, WoutT[0], 512, 0, bout[0], h0b, 512, 0, NN, 512, nullptr, nullptr);
        else
            gemm_bf16<128, 0, true, true, true><<<dim3(4, mt128), blk, 0, stream>>>(
                (const void*)aggb, 512, 0, WoutT[1], 512, 0, bout[1], h1b, 512, 0, NN, 512, h0b, skip1);
    }

    // node_embeds = h1 @ Wfc + bfc (f32 out)
    gemm_bf16<128, 0, false, true, false><<<dim3(2, mt128), blk, 0, stream>>>(
        (const void*)h1b, 512, 0, WfcT, 512, 0, bfc, outf, 256, 0, NN, 512, nullptr, nullptr);

    // edge_embeds = relu(ea @ We1 + be1) @ We2 + be2, full 160000 rows (f32 A read directly)
    gemm_bf16<128, 1, true, true, false, true><<<dim3(4, mtE), blk, 0, stream>>>(
        (const void*)ea, 128, 0, We1T, 128, 0, be1, eintb, 512, 0, MEDGE, 128, nullptr, nullptr);
    gemm_bf16<128, 0, false, true, false><<<dim3(2, mtE), blk, 0, stream>>>(
        (const void*)eintb, 512, 0, We2T, 512, 0, be2,
        outf + 5120000, 256, 0, MEDGE, 512, nullptr, nullptr);
}

// Round 6
// 762.674 us; speedup vs baseline: 9.0599x; 1.1068x over previous
//
#include <hip/hip_runtime.h>
#include <cstdint>
#include <cstddef>

#define NN      20000
#define RR      4
#define EE      40000
#define CIN     256
#define CEDGE   128
#define HIDW    512
#define OUTW    256
#define NH      8
#define MEDGE   (RR*EE)
#define SCALEF  0.125f

typedef unsigned short u16;
typedef short s8v  __attribute__((ext_vector_type(8)));
typedef float f32x4 __attribute__((ext_vector_type(4)));

// ---- ws layout (BYTE offsets) ----
#define B_KQV   10240000ull             // 20000*1536*2 = 61,440,000
#define B_KREL  71680000ull             // 20000*2048*2 = 81,920,000 (wsumH overlays after alpha)
#define B_AGG   153600000ull            // 20000*512*2
#define B_H0    174080000ull            // 20000*512*2
#define B_H1    194560000ull            // 20000*512*2
#define B_ALPHA 215040000ull            // 160000*8*4 = 5,120,000 (f32)
#define B_LSE   220160000ull            // 20000*8*4 (f32); fillcnt overlay during CSR build
#define B_ROWP  220800000ull            // 20001*4 -> pad
#define B_EREC  220880128ull            // 160000*4
#define B_WTS   221520128ull            // bf16 weights, ~5.2 MB
#define WS_NEED 227000000ull

#define SZH ((size_t)NN * 256)          // elements per head-matrix (wsumH)

__device__ __forceinline__ u16 f2b(float f) {
    unsigned u = __float_as_uint(f);
    unsigned r = (u + 0x7FFFu + ((u >> 16) & 1u)) >> 16;
    return (u16)r;
}
__device__ __forceinline__ float b2f(u16 h) { return __uint_as_float(((unsigned)h) << 16); }
__device__ __forceinline__ float gelu_exact(float x) {
    return 0.5f * x * (1.0f + erff(x * 0.70710678118654752f));
}

// async global->LDS, 16 bytes per lane; LDS dest must be wave-uniform base
__device__ __forceinline__ void gl_lds16(const u16* g, u16* l) {
    __builtin_amdgcn_global_load_lds(
        (const __attribute__((address_space(1))) void*)g,
        (__attribute__((address_space(3))) void*)l, 16, 0, 0);
}

// =============== generic bf16 MFMA GEMM (global_load_lds + XOR-swizzled LDS) ===============
// A: M x K row-major (lda) — bf16, or f32 converted during staging when AF32.
// BT: N x K bf16 row-major (ldb). C: M x N (ldc). batched over blockIdx.z via strides.
// K%64==0, N%BN==0, M guarded (rows clamped on load).
// LDS layout: As[row][chunk] (chunk = 8 elems / 16B) holds global chunk (chunk ^ (row&7)).
// ACT: 0 none, 1 relu, 2 gelu. SKIP: out = g*out+(1-g)*skipx (bf16).
template<int BN, int ACT, bool OUTBF16, bool BIAS, bool SKIP, bool AF32 = false>
__global__ __launch_bounds__(256) void gemm_bf16(
    const void* __restrict__ Av, int lda, size_t astride,
    const u16* __restrict__ BT, int ldb, size_t bstride,
    const float* __restrict__ bias,
    void* __restrict__ Cv, int ldc, size_t cstride,
    int M, int K,
    const u16* __restrict__ skipx, const float* __restrict__ gatep)
{
    constexpr int FN = BN / 32;         // frags per wave along N (wave covers BN/2)
    constexpr int BI = BN / 32;         // B stage instructions per wave
    __shared__ __align__(16) u16 As[128 * 64];
    __shared__ __align__(16) u16 Bs[BN * 64];

    const int t = threadIdx.x, lane = t & 63, wid = t >> 6;
    const int m0 = blockIdx.y * 128, n0 = blockIdx.x * BN;
    const int z  = blockIdx.z;
    const u16*   Bz = BT + (size_t)z * bstride;
    const float* Af = (const float*)Av + (AF32 ? (size_t)z * astride : 0);
    const u16*   Au = (const u16*)Av   + (AF32 ? 0 : (size_t)z * astride);
    const int wm = wid >> 1, wn = wid & 1;

    // per-lane staging constants: lane covers row-in-group (lane>>3), swizzled k-chunk
    const int srow   = lane >> 3;
    const int schunk = (lane & 7) ^ srow;

    f32x4 acc[4][FN];
    #pragma unroll
    for (int i = 0; i < 4; ++i)
        #pragma unroll
        for (int j = 0; j < FN; ++j)
            acc[i][j] = (f32x4){0.f, 0.f, 0.f, 0.f};

    for (int k0 = 0; k0 < K; k0 += 64) {
        if (AF32) {
            // reg staging with f32->bf16 convert; write to swizzled chunk
            #pragma unroll
            for (int i = 0; i < 4; ++i) {
                int c = i * 256 + t;
                int row = c >> 3, cc = c & 7;
                int gr = m0 + row; gr = gr < M ? gr : M - 1;
                const float* Ap = Af + (size_t)gr * lda + k0 + cc * 8;
                float4 p = *(const float4*)Ap;
                float4 q = *(const float4*)(Ap + 4);
                s8v v;
                v[0] = (short)f2b(p.x); v[1] = (short)f2b(p.y);
                v[2] = (short)f2b(p.z); v[3] = (short)f2b(p.w);
                v[4] = (short)f2b(q.x); v[5] = (short)f2b(q.y);
                v[6] = (short)f2b(q.z); v[7] = (short)f2b(q.w);
                *(s8v*)&As[row * 64 + ((cc ^ (row & 7)) << 3)] = v;
            }
        } else {
            // async staging: 16 wave-instructions cover 128 rows x 64 k
            #pragma unroll
            for (int i = 0; i < 4; ++i) {
                int t4 = wid * 4 + i;
                int row = t4 * 8 + srow;
                int gr = m0 + row; gr = gr < M ? gr : M - 1;
                gl_lds16(Au + (size_t)gr * lda + k0 + schunk * 8, &As[t4 * 512]);
            }
        }
        #pragma unroll
        for (int i = 0; i < BI; ++i) {
            int tb = wid * BI + i;
            int col = n0 + tb * 8 + srow;
            gl_lds16(Bz + (size_t)col * ldb + k0 + schunk * 8, &Bs[tb * 512]);
        }
        __syncthreads();   // drains vmcnt (incl. global_load_lds) + lgkmcnt
        #pragma unroll
        for (int ks = 0; ks < 2; ++ks) {
            s8v af[4], bf[FN];
            #pragma unroll
            for (int i = 0; i < 4; ++i) {
                int arow = wm * 64 + i * 16 + (lane & 15);
                int ac   = (ks * 4 + (lane >> 4)) ^ (lane & 7);
                af[i] = *(const s8v*)&As[arow * 64 + ac * 8];
            }
            #pragma unroll
            for (int j = 0; j < FN; ++j) {
                int brow = wn * (BN / 2) + j * 16 + (lane & 15);
                int bc   = (ks * 4 + (lane >> 4)) ^ (lane & 7);
                bf[j] = *(const s8v*)&Bs[brow * 64 + bc * 8];
            }
            #pragma unroll
            for (int i = 0; i < 4; ++i)
                #pragma unroll
                for (int j = 0; j < FN; ++j)
                    acc[i][j] = __builtin_amdgcn_mfma_f32_16x16x32_bf16(af[i], bf[j], acc[i][j], 0, 0, 0);
        }
        __syncthreads();
    }

    float gate = 1.f, ogate = 0.f;
    if (SKIP) { float s = *gatep; gate = 1.f / (1.f + expf(-s)); ogate = 1.f - gate; }
    u16*   Cb = (u16*)Cv   + (size_t)z * cstride;
    float* Cf = (float*)Cv + (size_t)z * cstride;
    #pragma unroll
    for (int i = 0; i < 4; ++i) {
        int rbase = m0 + wm * 64 + i * 16 + (lane >> 4) * 4;
        #pragma unroll
        for (int j = 0; j < FN; ++j) {
            int col = n0 + wn * (BN / 2) + j * 16 + (lane & 15);
            float bv = BIAS ? bias[col] : 0.f;
            #pragma unroll
            for (int q = 0; q < 4; ++q) {
                int r = rbase + q;
                if (r >= M) continue;
                float v = acc[i][j][q] + bv;
                if (ACT == 1) v = fmaxf(v, 0.f);
                if (ACT == 2) v = gelu_exact(v);
                if (SKIP) v = gate * v + ogate * b2f(skipx[(size_t)r * ldc + col]);
                if (OUTBF16) Cb[(size_t)r * ldc + col] = f2b(v);
                else         Cf[(size_t)r * ldc + col] = v;
            }
        }
    }
}

// =============== fused edge MLP: out = relu(ea @ We1 + b1) @ We2 + b2 ===============
// 64 edge-rows per block, 4 waves. Interm never leaves LDS.
// Stage 1: I_c[64][128] = relu(Ae[64][128] @ We1T[c]^T + b1_c)  (wave owns 32 cols)
// Stage 2: out[64][256] += I_c @ We2T[:, c]^T                   (wave owns 64 cols)
// B-fragments read straight from global (L2-resident, no inter-wave redundancy).
__global__ __launch_bounds__(256) void edge_mlp(
    const float* __restrict__ ea, const u16* __restrict__ We1T,
    const float* __restrict__ b1, const u16* __restrict__ We2T,
    const float* __restrict__ b2, float* __restrict__ out)
{
    __shared__ __align__(16) u16 Ae[64 * 128];
    __shared__ __align__(16) u16 Ic[64 * 128];

    const int t = threadIdx.x, lane = t & 63, w = t >> 6;
    const int e0 = blockIdx.x * 64;
    const int l15 = lane & 15, l4 = lane >> 4;

    // ---- stage ea tile (f32 -> bf16, chunk-XOR swizzle) ----
    #pragma unroll
    for (int i = 0; i < 4; ++i) {
        int c = i * 256 + t;            // chunk index 0..1023
        int row = c >> 4, cc = c & 15;
        const float* Ap = ea + (size_t)(e0 + row) * 128 + cc * 8;
        float4 p = *(const float4*)Ap;
        float4 q = *(const float4*)(Ap + 4);
        s8v v;
        v[0] = (short)f2b(p.x); v[1] = (short)f2b(p.y);
        v[2] = (short)f2b(p.z); v[3] = (short)f2b(p.w);
        v[4] = (short)f2b(q.x); v[5] = (short)f2b(q.y);
        v[6] = (short)f2b(q.z); v[7] = (short)f2b(q.w);
        *(s8v*)&Ae[row * 128 + ((cc ^ (row & 7)) << 3)] = v;
    }
    __syncthreads();

    f32x4 acc2[4][4];
    #pragma unroll
    for (int m = 0; m < 4; ++m)
        #pragma unroll
        for (int n = 0; n < 4; ++n)
            acc2[m][n] = (f32x4){0.f, 0.f, 0.f, 0.f};

    for (int c = 0; c < 4; ++c) {
        // ---- stage 1: this wave computes I_c cols [w*32, w*32+32) ----
        f32x4 sacc[4][2];
        #pragma unroll
        for (int m = 0; m < 4; ++m)
            #pragma unroll
            for (int n = 0; n < 2; ++n)
                sacc[m][n] = (f32x4){0.f, 0.f, 0.f, 0.f};
        #pragma unroll
        for (int ks = 0; ks < 4; ++ks) {
            s8v af[4], bf[2];
            #pragma unroll
            for (int m = 0; m < 4; ++m) {
                int row = m * 16 + l15;
                int kc  = (ks * 4 + l4) ^ (row & 7);
                af[m] = *(const s8v*)&Ae[row * 128 + kc * 8];
            }
            #pragma unroll
            for (int n = 0; n < 2; ++n) {
                int col1 = c * 128 + w * 32 + n * 16 + l15;
                bf[n] = *(const s8v*)(We1T + (size_t)col1 * 128 + ks * 32 + l4 * 8);
            }
            #pragma unroll
            for (int m = 0; m < 4; ++m)
                #pragma unroll
                for (int n = 0; n < 2; ++n)
                    sacc[m][n] = __builtin_amdgcn_mfma_f32_16x16x32_bf16(af[m], bf[n], sacc[m][n], 0, 0, 0);
        }
        __syncthreads();   // prev chunk's stage-2 reads of Ic complete
        // write I_c to LDS with bias+relu (swizzled chunk layout)
        #pragma unroll
        for (int m = 0; m < 4; ++m) {
            #pragma unroll
            for (int n = 0; n < 2; ++n) {
                int col = w * 32 + n * 16 + l15;
                float bv = b1[c * 128 + col];
                #pragma unroll
                for (int q = 0; q < 4; ++q) {
                    int row = m * 16 + l4 * 4 + q;
                    float v = fmaxf(sacc[m][n][q] + bv, 0.f);
                    Ic[row * 128 + (((col >> 3) ^ (row & 7)) << 3) + (col & 7)] = f2b(v);
                }
            }
        }
        __syncthreads();
        // ---- stage 2: this wave accumulates out cols [w*64, w*64+64) ----
        #pragma unroll
        for (int ks = 0; ks < 4; ++ks) {
            s8v af[4], bf[4];
            #pragma unroll
            for (int m = 0; m < 4; ++m) {
                int row = m * 16 + l15;
                int kc  = (ks * 4 + l4) ^ (row & 7);
                af[m] = *(const s8v*)&Ic[row * 128 + kc * 8];
            }
            #pragma unroll
            for (int n = 0; n < 4; ++n) {
                int col = w * 64 + n * 16 + l15;
                bf[n] = *(const s8v*)(We2T + (size_t)col * 512 + c * 128 + ks * 32 + l4 * 8);
            }
            #pragma unroll
            for (int m = 0; m < 4; ++m)
                #pragma unroll
                for (int n = 0; n < 4; ++n)
                    acc2[m][n] = __builtin_amdgcn_mfma_f32_16x16x32_bf16(af[m], bf[n], acc2[m][n], 0, 0, 0);
        }
    }

    // ---- epilogue: bias + f32 store ----
    #pragma unroll
    for (int m = 0; m < 4; ++m) {
        #pragma unroll
        for (int n = 0; n < 4; ++n) {
            int col = w * 64 + n * 16 + l15;
            float bv = b2[col];
            #pragma unroll
            for (int q = 0; q < 4; ++q) {
                int row = m * 16 + l4 * 4 + q;
                out[(size_t)(e0 + row) * 256 + col] = acc2[m][n][q] + bv;
            }
        }
    }
}

// =============== weight conversions ===============
// W [K x N] f32 -> WT [N x K] bf16
__global__ __launch_bounds__(256) void transpose_f2b(
    const float* __restrict__ W, u16* __restrict__ WT, int K, int N)
{
    __shared__ float tile[32][33];
    int kb = blockIdx.x * 32, nb = blockIdx.y * 32;
    int tx = threadIdx.x & 31, ty = threadIdx.x >> 5;   // ty 0..7
    #pragma unroll
    for (int i = 0; i < 32; i += 8)
        tile[ty + i][tx] = W[(size_t)(kb + ty + i) * N + nb + tx];
    __syncthreads();
    #pragma unroll
    for (int i = 0; i < 32; i += 8)
        WT[(size_t)(nb + ty + i) * K + kb + tx] = f2b(tile[tx][ty + i]);
}

// Wk[r][h][d][e] -> WkT[h][r*64+e][d]
__global__ void conv_wk(const float* __restrict__ Wk, u16* __restrict__ WkT)
{
    int idx = blockIdx.x * 256 + threadIdx.x;
    if (idx >= 8 * 256 * 64) return;
    int d = idx & 63, re = (idx >> 6) & 255, h = idx >> 14;
    int e = re & 63, r = re >> 6;
    WkT[idx] = f2b(Wk[(size_t)(((r * 8 + h) * 64 + d) * 64) + e]);
}

// Wv[r][h][d][e] -> WvT[h][e][r*64+d]
__global__ void conv_wv(const float* __restrict__ Wv, u16* __restrict__ WvT)
{
    int idx = blockIdx.x * 256 + threadIdx.x;
    if (idx >= 8 * 64 * 256) return;
    int d = idx & 63, r = (idx >> 6) & 3, e = (idx >> 8) & 63, h = idx >> 14;
    WvT[idx] = f2b(Wv[(size_t)(((r * 8 + h) * 64 + d) * 64) + e]);
}

// =============== CSR build ===============
__global__ void deg_kernel(const int* __restrict__ ei, int* __restrict__ rowptr)
{
    int idx = blockIdx.x * 256 + threadIdx.x;
    if (idx >= MEDGE) return;
    int r = idx / EE;
    atomicAdd(&rowptr[ei[idx + (r + 1) * EE]], 1);
}

__global__ __launch_bounds__(256) void scan_kernel(int* __restrict__ rowptr)
{
    __shared__ int buf[256];
    __shared__ int carry;
    const int t = threadIdx.x;
    if (t == 0) carry = 0;
    __syncthreads();
    for (int base = 0; base < NN; base += 256) {
        int i = base + t;
        int v = (i < NN) ? rowptr[i] : 0;
        buf[t] = v;
        __syncthreads();
        for (int off = 1; off < 256; off <<= 1) {
            int tv = (t >= off) ? buf[t - off] : 0;
            __syncthreads();
            buf[t] += tv;
            __syncthreads();
        }
        int total = buf[255];
        int excl = buf[t] - v;
        int c = carry;
        __syncthreads();
        if (i < NN) rowptr[i] = c + excl;
        if (t == 0) carry = c + total;
        __syncthreads();
    }
    if (t == 0) rowptr[NN] = carry;
}

__global__ void fill_kernel(const int* __restrict__ ei, const int* __restrict__ rowptr,
                            int* __restrict__ fillcnt, int* __restrict__ erec)
{
    int idx = blockIdx.x * 256 + threadIdx.x;
    if (idx >= MEDGE) return;
    int r = idx / EE;
    int dst = ei[idx + (r + 1) * EE];
    int pos = rowptr[dst] + atomicAdd(&fillcnt[dst], 1);
    erec[pos] = idx;
}

// =============== fused alpha + online-LSE (all relations; wave per node) ===============
// krel2 layout: [n][h*256 + r*64 + d] bf16 (one 2KB row per src node)
__global__ __launch_bounds__(256) void alpha_stats(
    const u16* __restrict__ krel2, const u16* __restrict__ kqvb,
    const int* __restrict__ ei, const int* __restrict__ rowptr,
    const int* __restrict__ erec, const float* __restrict__ prel,
    float* __restrict__ alpha, float* __restrict__ lse)
{
    int n    = (blockIdx.x * 256 + threadIdx.x) >> 6;
    int lane = threadIdx.x & 63;
    if (n >= NN) return;
    int p0 = rowptr[n], p1 = rowptr[n + 1];
    int h = lane >> 3, sub = lane & 7;
    s8v qv = *(const s8v*)(kqvb + (size_t)n * 1536 + 512 + h * 64 + sub * 8);
    float qf[8];
    #pragma unroll
    for (int q = 0; q < 8; ++q) qf[q] = b2f((u16)qv[q]);
    float m = -3.0e38f, ssum = 0.f;
    for (int j = p0; j < p1; ++j) {
        int idx = erec[j];
        int r = idx / EE;
        int src = ei[idx + r * EE];
        s8v kv = *(const s8v*)(krel2 + (size_t)src * 2048 + h * 256 + r * 64 + sub * 8);
        float s = 0.f;
        #pragma unroll
        for (int q = 0; q < 8; ++q) s += b2f((u16)kv[q]) * qf[q];
        s += __shfl_xor(s, 1);
        s += __shfl_xor(s, 2);
        s += __shfl_xor(s, 4);
        float a = s * prel[r * NH + h] * SCALEF;
        if (sub == 0) alpha[(size_t)idx * 8 + h] = a;
        float mn = fmaxf(m, a);
        ssum = ssum * expf(m - mn) + expf(a - mn);
        m = mn;
    }
    if (sub == 0) lse[(size_t)n * 8 + h] = m + logf(ssum + 1e-16f);
}

// =============== weighted v aggregation (all relations; wave per node; one CSR scan) ===============
// writes wsumH[h][n][r*64 + d] bf16
__global__ __launch_bounds__(256) void wsum_all(
    const u16* __restrict__ kqvb, const float* __restrict__ alpha,
    const float* __restrict__ lse, const int* __restrict__ rowptr,
    const int* __restrict__ erec, const int* __restrict__ ei,
    u16* __restrict__ wsumH)
{
    int n    = (blockIdx.x * 256 + threadIdx.x) >> 6;
    int lane = threadIdx.x & 63;
    if (n >= NN) return;
    int p0 = rowptr[n], p1 = rowptr[n + 1];
    int h = lane >> 3;
    float ls = lse[(size_t)n * 8 + h];
    float a0[8] = {}, a1[8] = {}, a2[8] = {}, a3[8] = {};
    for (int j = p0; j < p1; ++j) {
        int idx = erec[j];
        int r = idx / EE;                 // wave-uniform
        int src = ei[idx + r * EE];
        float w = expf(alpha[(size_t)idx * 8 + h] - ls);
        s8v vv = *(const s8v*)(kqvb + (size_t)src * 1536 + 1024 + lane * 8);
        if (r == 0) {
            #pragma unroll
            for (int q = 0; q < 8; ++q) a0[q] += w * b2f((u16)vv[q]);
        } else if (r == 1) {
            #pragma unroll
            for (int q = 0; q < 8; ++q) a1[q] += w * b2f((u16)vv[q]);
        } else if (r == 2) {
            #pragma unroll
            for (int q = 0; q < 8; ++q) a2[q] += w * b2f((u16)vv[q]);
        } else {
            #pragma unroll
            for (int q = 0; q < 8; ++q) a3[q] += w * b2f((u16)vv[q]);
        }
    }
    u16* base = wsumH + (size_t)h * SZH + (size_t)n * 256 + (lane & 7) * 8;
    s8v o;
    #pragma unroll
    for (int q = 0; q < 8; ++q) o[q] = (short)f2b(a0[q]);
    *(s8v*)(base + 0)   = o;
    #pragma unroll
    for (int q = 0; q < 8; ++q) o[q] = (short)f2b(a1[q]);
    *(s8v*)(base + 64)  = o;
    #pragma unroll
    for (int q = 0; q < 8; ++q) o[q] = (short)f2b(a2[q]);
    *(s8v*)(base + 128) = o;
    #pragma unroll
    for (int q = 0; q < 8; ++q) o[q] = (short)f2b(a3[q]);
    *(s8v*)(base + 192) = o;
}

extern "C" void kernel_launch(void* const* d_in, const int* in_sizes, int n_in,
                              void* d_out, int out_size, void* d_ws, size_t ws_size,
                              hipStream_t stream)
{
    const float* x    = (const float*)d_in[0];
    const int*   ei   = (const int*)d_in[1];
    const float* ea   = (const float*)d_in[2];
    const float* Wkqv[2] = {(const float*)d_in[3],  (const float*)d_in[10]};
    const float* bkqv[2] = {(const float*)d_in[4],  (const float*)d_in[11]};
    const float* Wk[2]   = {(const float*)d_in[5],  (const float*)d_in[12]};
    const float* Wv[2]   = {(const float*)d_in[6],  (const float*)d_in[13]};
    const float* prel[2] = {(const float*)d_in[7],  (const float*)d_in[14]};
    const float* Wout[2] = {(const float*)d_in[8],  (const float*)d_in[15]};
    const float* bout[2] = {(const float*)d_in[9],  (const float*)d_in[16]};
    const float* skip1 = (const float*)d_in[17];
    const float* Wfc   = (const float*)d_in[18];
    const float* bfc   = (const float*)d_in[19];
    const float* We1   = (const float*)d_in[20];
    const float* be1   = (const float*)d_in[21];
    const float* We2   = (const float*)d_in[22];
    const float* be2   = (const float*)d_in[23];

    if (ws_size < WS_NEED) return;

    char* wsb = (char*)d_ws;
    u16*   kqvb  = (u16*)(wsb + B_KQV);
    u16*   krel2 = (u16*)(wsb + B_KREL);
    u16*   wsumH = krel2;                    // overlay (krel dead after alpha_stats)
    u16*   aggb  = (u16*)(wsb + B_AGG);
    u16*   h0b   = (u16*)(wsb + B_H0);
    u16*   h1b   = (u16*)(wsb + B_H1);
    float* alpha = (float*)(wsb + B_ALPHA);
    float* lse   = (float*)(wsb + B_LSE);
    int*   fillcnt = (int*)(wsb + B_LSE);    // build-time overlay
    int*   rowptr  = (int*)(wsb + B_ROWP);
    int*   erec    = (int*)(wsb + B_EREC);
    float* outf  = (float*)d_out;

    // bf16 weight arena
    u16* wt = (u16*)(wsb + B_WTS);
    u16* WkqvT[2] = {wt, wt + 393216};              wt += 393216 + 786432;
    u16* WkT[2]   = {wt, wt + 131072};              wt += 262144;
    u16* WvT[2]   = {wt, wt + 131072};              wt += 262144;
    u16* WoutT[2] = {wt, wt + 262144};              wt += 524288;
    u16* WfcT     = wt;                             wt += 131072;
    u16* We1T     = wt;                             wt += 65536;
    u16* We2T     = wt;

    const dim3 blk(256);
    const int mt128  = (NN + 127) / 128;   // 157

    // ---- weight conversions ----
    transpose_f2b<<<dim3(CIN / 32, 1536 / 32), blk, 0, stream>>>(Wkqv[0], WkqvT[0], CIN, 1536);
    transpose_f2b<<<dim3(HIDW / 32, 1536 / 32), blk, 0, stream>>>(Wkqv[1], WkqvT[1], HIDW, 1536);
    transpose_f2b<<<dim3(HIDW / 32, HIDW / 32), blk, 0, stream>>>(Wout[0], WoutT[0], HIDW, HIDW);
    transpose_f2b<<<dim3(HIDW / 32, HIDW / 32), blk, 0, stream>>>(Wout[1], WoutT[1], HIDW, HIDW);
    transpose_f2b<<<dim3(HIDW / 32, OUTW / 32), blk, 0, stream>>>(Wfc, WfcT, HIDW, OUTW);
    transpose_f2b<<<dim3(CEDGE / 32, HIDW / 32), blk, 0, stream>>>(We1, We1T, CEDGE, HIDW);
    transpose_f2b<<<dim3(HIDW / 32, OUTW / 32), blk, 0, stream>>>(We2, We2T, HIDW, OUTW);
    for (int l = 0; l < 2; ++l) {
        conv_wk<<<(131072 + 255) / 256, blk, 0, stream>>>(Wk[l], WkT[l]);
        conv_wv<<<(131072 + 255) / 256, blk, 0, stream>>>(Wv[l], WvT[l]);
    }

    // ---- CSR build ----
    hipMemsetAsync(rowptr, 0, (NN + 1) * sizeof(int), stream);
    hipMemsetAsync(fillcnt, 0, NN * sizeof(int), stream);
    deg_kernel<<<(MEDGE + 255) / 256, blk, 0, stream>>>(ei, rowptr);
    scan_kernel<<<1, blk, 0, stream>>>(rowptr);
    fill_kernel<<<(MEDGE + 255) / 256, blk, 0, stream>>>(ei, rowptr, fillcnt, erec);

    for (int l = 0; l < 2; ++l) {
        int K = (l == 0) ? CIN : HIDW;

        // kqv = xin @ Wkqv + b  -> bf16 [20000 x 1536]   (layer 0 reads f32 x directly)
        if (l == 0)
            gemm_bf16<128, 0, true, true, false, true><<<dim3(12, mt128), blk, 0, stream>>>(
                (const void*)x, K, 0, WkqvT[0], K, 0, bkqv[0], kqvb, 1536, 0, NN, K, nullptr, nullptr);
        else
            gemm_bf16<128, 0, true, true, false><<<dim3(12, mt128), blk, 0, stream>>>(
                (const void*)h0b, K, 0, WkqvT[1], K, 0, bkqv[1], kqvb, 1536, 0, NN, K, nullptr, nullptr);

        // k_rel (all relations): per-head batched GEMM, K=64, N=256; out [n][h*256+r*64+e]
        gemm_bf16<128, 0, true, false, false><<<dim3(2, mt128, NH), blk, 0, stream>>>(
            (const void*)kqvb, 1536, 64, WkT[l], 64, (size_t)256 * 64, nullptr,
            krel2, 2048, 256, NN, 64, nullptr, nullptr);

        alpha_stats<<<(NN * 64) / 256, blk, 0, stream>>>(
            krel2, kqvb, ei, rowptr, erec, prel[l], alpha, lse);

        wsum_all<<<(NN * 64) / 256, blk, 0, stream>>>(
            kqvb, alpha, lse, rowptr, erec, ei, wsumH);

        // agg = gelu( sum_r wsum_r @ Wv_r ) : per-head batched GEMM, K=256, N=64
        gemm_bf16<64, 2, true, false, false><<<dim3(1, mt128, NH), blk, 0, stream>>>(
            (const void*)wsumH, 256, SZH, WvT[l], 256, (size_t)64 * 256, nullptr,
            aggb, 512, 64, NN, 256, nullptr, nullptr);

        // out = agg @ Wout + bout (+ skip mix on layer 1)
        if (l == 0)
            gemm_bf16<128, 0, true, true, false><<<dim3(4, mt128), blk, 0, stream>>>(
                (const void*)aggb, 512, 0, WoutT[0], 512, 0, bout[0], h0b, 512, 0, NN, 512, nullptr, nullptr);
        else
            gemm_bf16<128, 0, true, true, true><<<dim3(4, mt128), blk, 0, stream>>>(
                (const void*)aggb, 512, 0, WoutT[1], 512, 0, bout[1], h1b, 512, 0, NN, 512, h0b, skip1);
    }

    // node_embeds = h1 @ Wfc + bfc (f32 out)
    gemm_bf16<128, 0, false, true, false><<<dim3(2, mt128), blk, 0, stream>>>(
        (const void*)h1b, 512, 0, WfcT, 512, 0, bfc, outf, 256, 0, NN, 512, nullptr, nullptr);

    // edge_embeds = relu(ea @ We1 + be1) @ We2 + be2 — fully fused, interm stays in LDS
    edge_mlp<<<MEDGE / 64, blk, 0, stream>>>(ea, We1T, be1, We2T, be2, outf + 5120000);
}